// Round 5
// baseline (1009.187 us; speedup 1.0000x reference)
//
#include <hip/hip_runtime.h>

// GAT (2 layers, heads=1) + 2-layer MLP head. N=100000, E=3200000, D=128.
// R5: 64-node buckets, 4-lanes-per-edge float4 gathers, x4 unrolled edge loop
// (ILP latency hiding), LDS accumulators with odd row stride (bank spread).
// Softmax stabilization uses a GLOBAL upper bound m̄_i = leaky(gmax_asrc + adst_i)
// (valid since leaky_relu is monotone); alpha is mathematically unchanged.

#define NEG 0.2f
#define BSH 6
#define BNODES 64            // nodes per bucket
#define MAXB 1600            // >= ceil(100000/64)=1563
#define ROW 19               // LDS accumulator row stride: 16 feat + den@16 + pad (odd)

__device__ __forceinline__ float lrelu(float x) { return x > 0.0f ? x : NEG * x; }

__device__ __forceinline__ unsigned fenc(float f) {
    unsigned u = __float_as_uint(f);
    return (u & 0x80000000u) ? ~u : (u | 0x80000000u);
}
__device__ __forceinline__ float fdec(unsigned e) {
    return (e & 0x80000000u) ? __uint_as_float(e & 0x7FFFFFFFu) : __uint_as_float(~e);
}

__global__ __launch_bounds__(256) void k_init(unsigned* g, int* bcnt, int NB) {
    int i = blockIdx.x * 256 + threadIdx.x;
    if (i < NB) bcnt[i] = 0;
    if (i < 2) g[i] = 0u;
}

// K1: h1 = x @ W1 (128->16), s1 = h1·a1s, d1 = h1·a1d, gmax1 = max(s1)
__global__ __launch_bounds__(256) void k_gemm1(
    const float* __restrict__ x, const float* __restrict__ W1,
    const float* __restrict__ a1s, const float* __restrict__ a1d,
    float* __restrict__ h1, float* __restrict__ s1, float* __restrict__ d1,
    unsigned* __restrict__ gmax, int N)
{
    __shared__ float sW[128 * 16];
    __shared__ float sx[64 * 132];
    __shared__ float wm[4];
    int tid = threadIdx.x;
    for (int i = tid; i < 2048; i += 256) sW[i] = W1[i];
    int node0 = blockIdx.x * 64;
    for (int i = tid; i < 64 * 32; i += 256) {
        int row = i >> 5, c4 = i & 31;
        int n = node0 + row;
        float4 v = make_float4(0.f, 0.f, 0.f, 0.f);
        if (n < N) v = ((const float4*)x)[(size_t)n * 32 + c4];
        *(float4*)&sx[row * 132 + c4 * 4] = v;
    }
    __syncthreads();

    int node = node0 + (tid >> 2);
    int grp  = tid & 3;
    const float* xr = &sx[(tid >> 2) * 132];
    float4 acc = make_float4(0.f, 0.f, 0.f, 0.f);
#pragma unroll 8
    for (int j = 0; j < 128; ++j) {
        float xv = xr[j];
        float4 w = *(const float4*)&sW[j * 16 + grp * 4];
        acc.x += xv * w.x; acc.y += xv * w.y; acc.z += xv * w.z; acc.w += xv * w.w;
    }
    float4 as = ((const float4*)a1s)[grp];
    float4 ad = ((const float4*)a1d)[grp];
    float sv = acc.x * as.x + acc.y * as.y + acc.z * as.z + acc.w * as.w;
    float dv = acc.x * ad.x + acc.y * ad.y + acc.z * ad.z + acc.w * ad.w;
    sv += __shfl_xor(sv, 1); sv += __shfl_xor(sv, 2);
    dv += __shfl_xor(dv, 1); dv += __shfl_xor(dv, 2);
    if (node < N) {
        *(float4*)&h1[(size_t)node * 16 + grp * 4] = acc;
        if (grp == 0) { s1[node] = sv; d1[node] = dv; }
    }
    float m = (node < N) ? sv : -3.4e38f;
#pragma unroll
    for (int off = 32; off >= 1; off >>= 1) m = fmaxf(m, __shfl_xor(m, off));
    if ((tid & 63) == 0) wm[tid >> 6] = m;
    __syncthreads();
    if (tid == 0) {
        float b = fmaxf(fmaxf(wm[0], wm[1]), fmaxf(wm[2], wm[3]));
        atomicMax(gmax, fenc(b));
    }
}

// bucket histogram, LDS-aggregated
__global__ __launch_bounds__(256) void k_bcount(const int* __restrict__ edst,
                                                int* __restrict__ bcnt, int E, int NB) {
    __shared__ int lc[MAXB];
    int tid = threadIdx.x;
    for (int i = tid; i < NB; i += 256) lc[i] = 0;
    __syncthreads();
    int stride = gridDim.x * 256;
    for (int e = blockIdx.x * 256 + tid; e < E; e += stride)
        atomicAdd(&lc[edst[e] >> BSH], 1);
    __syncthreads();
    for (int i = tid; i < NB; i += 256) { int v = lc[i]; if (v) atomicAdd(&bcnt[i], v); }
}

// exclusive scan of bucket counts -> boffs[NB+1]; init padded cursors
__global__ __launch_bounds__(256) void k_boffs(const int* __restrict__ bcnt,
                                               int* __restrict__ boffs, int* __restrict__ bcur,
                                               int NB, int E) {
    __shared__ int l[MAXB + 1];
    int tid = threadIdx.x;
    for (int i = tid; i < NB; i += 256) l[i] = bcnt[i];
    __syncthreads();
    if (tid == 0) { int run = 0; for (int i = 0; i < NB; ++i) { int c = l[i]; l[i] = run; run += c; } l[NB] = run; }
    __syncthreads();
    for (int i = tid; i < NB; i += 256) { boffs[i] = l[i]; bcur[i * 16] = l[i]; }
    if (tid == 0) boffs[NB] = E;
}

// scatter packed (dstlow<<17 | src) into bucket regions
__global__ __launch_bounds__(256) void k_bscatter(const int* __restrict__ esrc,
                                                  const int* __restrict__ edst,
                                                  int* __restrict__ bcur,
                                                  unsigned* __restrict__ pairs, int E) {
    int e = blockIdx.x * 256 + threadIdx.x;
    if (e >= E) return;
    int d = edst[e], s = esrc[e];
    int pos = atomicAdd(&bcur[(d >> BSH) * 16], 1);
    pairs[pos] = ((unsigned)(d & (BNODES - 1)) << 17) | (unsigned)s;
}

// ---- layer-1 aggregation + norm+bias+relu + layer-2 GEMM/scores ----
__global__ __launch_bounds__(256) void k_agg1(
    const int* __restrict__ boffs, const unsigned* __restrict__ pairs,
    const float* __restrict__ s1, const float* __restrict__ d1, const float* __restrict__ h1,
    const float* __restrict__ b1, const float* __restrict__ W2,
    const float* __restrict__ a2s, const float* __restrict__ a2d,
    float* __restrict__ h2, float* __restrict__ s2, float* __restrict__ d2,
    const unsigned* __restrict__ gmax1p, unsigned* __restrict__ gmax2, int N)
{
    __shared__ float acc[BNODES * ROW];     // 16 feat + den at [16]
    __shared__ float dds[BNODES], mbs[BNODES];
    __shared__ float sW[160], sb[16], sas[16], sad[16];
    __shared__ float wm[4];
    int tid = threadIdx.x;
    if (tid < 160) sW[tid] = W2[tid];
    if (tid < 16) {
        sb[tid]  = b1[tid];
        sas[tid] = (tid < 10) ? a2s[tid] : 0.f;
        sad[tid] = (tid < 10) ? a2d[tid] : 0.f;
    }
    int node0 = blockIdx.x << BSH;
    float g0 = fdec(*gmax1p);
    if (tid < BNODES) {
        int n = node0 + tid;
        float dd = (n < N) ? d1[n] : 0.f;
        dds[tid] = dd; mbs[tid] = lrelu(g0 + dd);
    }
    __syncthreads();

    int eg = tid >> 2, q = tid & 3;         // 64 edge-slots x 4 lanes
    // self-loop init (4 lanes per node, once)
    {
        int nl = eg, n = node0 + nl;
        if (n < N) {
            float w = __expf(lrelu(s1[n] + dds[nl]) - mbs[nl]);
            float4 hv = *(const float4*)&h1[(size_t)n * 16 + 4 * q];
            float* r = &acc[nl * ROW + 4 * q];
            r[0] = w * hv.x; r[1] = w * hv.y; r[2] = w * hv.z; r[3] = w * hv.w;
            if (q == 0) acc[nl * ROW + 16] = w;
        }
    }
    __syncthreads();

    int jbeg = boffs[blockIdx.x], jend = boffs[blockIdx.x + 1];
    for (int j0 = jbeg; j0 < jend; j0 += 256) {
        unsigned p[4]; float svv[4]; float4 hv[4]; int ok[4];
#pragma unroll
        for (int u = 0; u < 4; ++u) {
            int j = j0 + u * 64 + eg;
            ok[u] = (j < jend);
            p[u] = ok[u] ? pairs[j] : 0u;
        }
#pragma unroll
        for (int u = 0; u < 4; ++u) {
            int src = p[u] & 0x1FFFF;
            svv[u] = ok[u] ? s1[src] : 0.f;
        }
#pragma unroll
        for (int u = 0; u < 4; ++u) {
            int src = p[u] & 0x1FFFF;
            hv[u] = ok[u] ? *(const float4*)&h1[(size_t)src * 16 + 4 * q]
                          : make_float4(0.f, 0.f, 0.f, 0.f);
        }
#pragma unroll
        for (int u = 0; u < 4; ++u) {
            if (!ok[u]) continue;
            int nl = (p[u] >> 17) & (BNODES - 1);
            float w = __expf(lrelu(svv[u] + dds[nl]) - mbs[nl]);
            float* r = &acc[nl * ROW + 4 * q];
            atomicAdd(r + 0, w * hv[u].x);
            atomicAdd(r + 1, w * hv[u].y);
            atomicAdd(r + 2, w * hv[u].z);
            atomicAdd(r + 3, w * hv[u].w);
            if (q == 0) atomicAdd(&acc[nl * ROW + 16], w);
        }
    }
    __syncthreads();

    // epilogue: 16 groups of 16 lanes, 4 nodes per group
    int g = tid >> 4, k = tid & 15;
    float sval = -3.4e38f;
#pragma unroll
    for (int qq = 0; qq < 4; ++qq) {
        int nl = g * 4 + qq, n = node0 + nl;
        if (n >= N) continue;               // group-uniform
        float inv = 1.f / acc[nl * ROW + 16];
        float o = fmaxf(acc[nl * ROW + k] * inv + sb[k], 0.f);
        float hh = 0.f;
#pragma unroll
        for (int kk = 0; kk < 16; ++kk) {
            float ov = __shfl(o, kk, 16);
            if (k < 10) hh += ov * sW[kk * 10 + k];
        }
        if (k >= 10) hh = 0.f;
        float ts = hh * sas[k];
        float td = hh * sad[k];
#pragma unroll
        for (int off = 1; off < 16; off <<= 1) {
            ts += __shfl_xor(ts, off, 16);
            td += __shfl_xor(td, off, 16);
        }
        h2[(size_t)n * 16 + k] = hh;        // zero-padded cols 10..15
        if (k == 0) { s2[n] = ts; d2[n] = td; }
        sval = fmaxf(sval, ts);
    }
    float m = sval;
#pragma unroll
    for (int off = 32; off >= 1; off >>= 1) m = fmaxf(m, __shfl_xor(m, off));
    if ((tid & 63) == 0) wm[tid >> 6] = m;
    __syncthreads();
    if (tid == 0)
        atomicMax(gmax2, fenc(fmaxf(fmaxf(wm[0], wm[1]), fmaxf(wm[2], wm[3]))));
}

// ---- layer-2 aggregation + norm+bias + MLP head -> out ----
__global__ __launch_bounds__(256) void k_agg2(
    const int* __restrict__ boffs, const unsigned* __restrict__ pairs,
    const float* __restrict__ s2, const float* __restrict__ d2, const float* __restrict__ h2,
    const float* __restrict__ b2, const float* __restrict__ Wl1, const float* __restrict__ bl1,
    const float* __restrict__ Wl2, const float* __restrict__ bl2,
    const unsigned* __restrict__ gmax2p, float* __restrict__ out, int N)
{
    __shared__ float acc[BNODES * ROW];
    __shared__ float dds[BNODES], mbs[BNODES];
    __shared__ float sW1[100], sb1[16], sW2[16], sb2g[16];
    __shared__ float sbl2;
    int tid = threadIdx.x;
    if (tid < 100) sW1[tid] = Wl1[tid];
    if (tid < 16) {
        sb1[tid]  = (tid < 10) ? bl1[tid] : 0.f;
        sW2[tid]  = (tid < 10) ? Wl2[tid] : 0.f;
        sb2g[tid] = (tid < 10) ? b2[tid]  : 0.f;
    }
    if (tid == 0) sbl2 = bl2[0];
    int node0 = blockIdx.x << BSH;
    float g0 = fdec(*gmax2p);
    if (tid < BNODES) {
        int n = node0 + tid;
        float dd = (n < N) ? d2[n] : 0.f;
        dds[tid] = dd; mbs[tid] = lrelu(g0 + dd);
    }
    __syncthreads();

    int eg = tid >> 2, q = tid & 3;
    {
        int nl = eg, n = node0 + nl;
        if (n < N) {
            float w = __expf(lrelu(s2[n] + dds[nl]) - mbs[nl]);
            float4 hv = *(const float4*)&h2[(size_t)n * 16 + 4 * q];  // zero-padded
            float* r = &acc[nl * ROW + 4 * q];
            r[0] = w * hv.x; r[1] = w * hv.y; r[2] = w * hv.z; r[3] = w * hv.w;
            if (q == 0) acc[nl * ROW + 16] = w;
        }
    }
    __syncthreads();

    int jbeg = boffs[blockIdx.x], jend = boffs[blockIdx.x + 1];
    for (int j0 = jbeg; j0 < jend; j0 += 256) {
        unsigned p[4]; float svv[4]; float4 hv[4]; int ok[4];
#pragma unroll
        for (int u = 0; u < 4; ++u) {
            int j = j0 + u * 64 + eg;
            ok[u] = (j < jend);
            p[u] = ok[u] ? pairs[j] : 0u;
        }
#pragma unroll
        for (int u = 0; u < 4; ++u) {
            int src = p[u] & 0x1FFFF;
            svv[u] = ok[u] ? s2[src] : 0.f;
        }
#pragma unroll
        for (int u = 0; u < 4; ++u) {
            int src = p[u] & 0x1FFFF;
            hv[u] = ok[u] ? *(const float4*)&h2[(size_t)src * 16 + 4 * q]
                          : make_float4(0.f, 0.f, 0.f, 0.f);
        }
#pragma unroll
        for (int u = 0; u < 4; ++u) {
            if (!ok[u]) continue;
            int nl = (p[u] >> 17) & (BNODES - 1);
            float w = __expf(lrelu(svv[u] + dds[nl]) - mbs[nl]);
            float* r = &acc[nl * ROW + 4 * q];
            atomicAdd(r + 0, w * hv[u].x);
            atomicAdd(r + 1, w * hv[u].y);
            atomicAdd(r + 2, w * hv[u].z);
            atomicAdd(r + 3, w * hv[u].w);
            if (q == 0) atomicAdd(&acc[nl * ROW + 16], w);
        }
    }
    __syncthreads();

    int g = tid >> 4, k = tid & 15;
    bool fk = k < 10;
#pragma unroll
    for (int qq = 0; qq < 4; ++qq) {
        int nl = g * 4 + qq, n = node0 + nl;
        if (n >= N) continue;               // group-uniform
        float inv = 1.f / acc[nl * ROW + 16];
        float o = fk ? acc[nl * ROW + k] * inv + sb2g[k] : 0.f;
        float v = sb1[k];
#pragma unroll
        for (int kk = 0; kk < 10; ++kk) {
            float ov = __shfl(o, kk, 16);
            if (fk) v += ov * sW1[kk * 10 + k];
        }
        float t = fmaxf(v, 0.f);
        float c = t * sW2[k];               // zero for k>=10
#pragma unroll
        for (int off = 1; off < 16; off <<= 1) c += __shfl_xor(c, off, 16);
        if (k == 0) out[n] = c + sbl2;
    }
}

extern "C" void kernel_launch(void* const* d_in, const int* in_sizes, int n_in,
                              void* d_out, int out_size, void* d_ws, size_t ws_size,
                              hipStream_t stream)
{
    const float* x   = (const float*)d_in[0];
    const int*   ei  = (const int*)  d_in[1];   // [2][E] int32
    const float* W1  = (const float*)d_in[2];
    const float* a1s = (const float*)d_in[3];
    const float* a1d = (const float*)d_in[4];
    const float* b1  = (const float*)d_in[5];
    const float* W2  = (const float*)d_in[6];
    const float* a2s = (const float*)d_in[7];
    const float* a2d = (const float*)d_in[8];
    const float* b2  = (const float*)d_in[9];
    const float* Wl1 = (const float*)d_in[10];
    const float* bl1 = (const float*)d_in[11];
    const float* Wl2 = (const float*)d_in[12];
    const float* bl2 = (const float*)d_in[13];

    int N = in_sizes[0] / 128;
    int E = in_sizes[1] / 2;
    const int* ei_src = ei;
    const int* ei_dst = ei + E;
    int NB = (N + BNODES - 1) >> BSH;       // 1563 for N=100000

    size_t Np = ((size_t)N + 3) & ~(size_t)3;      // keep 16B alignment of 16-wide rows
    size_t N16 = Np * 16;
    // ws: 16 + 36Np floats + 18NB+1 ints + E u32
    size_t need_bytes = (16 + Np * 36) * 4 + ((size_t)NB * 18 + 1) * 4 + (size_t)E * 4;
    if (ws_size < need_bytes) return;  // degrade to wrong-answer, never fault

    float*    ws    = (float*)d_ws;
    unsigned* gmax1 = (unsigned*)d_ws;       // [0]
    unsigned* gmax2 = gmax1 + 1;             // [1]
    float* h1 = ws + 16;                     // Np*16  (16B-aligned rows)
    float* s1 = h1 + N16;                    // Np
    float* d1 = s1 + Np;                     // Np
    float* h2 = d1 + Np;                     // Np*16  (cols 10..15 zero)
    float* s2 = h2 + N16;                    // Np
    float* d2 = s2 + Np;                     // Np
    int* bcnt  = (int*)(d2 + Np);            // NB
    int* boffs = bcnt + NB;                  // NB+1
    int* bcur  = boffs + NB + 1;             // NB*16 (1 cursor per 64B)
    unsigned* pairs = (unsigned*)(bcur + (size_t)NB * 16);  // E

    int eblk = (E + 255) / 256;

    hipLaunchKernelGGL(k_init, dim3((NB + 255) / 256), dim3(256), 0, stream, gmax1, bcnt, NB);
    hipLaunchKernelGGL(k_gemm1, dim3((N + 63) / 64), dim3(256), 0, stream,
                       x, W1, a1s, a1d, h1, s1, d1, gmax1, N);
    hipLaunchKernelGGL(k_bcount, dim3(256), dim3(256), 0, stream, ei_dst, bcnt, E, NB);
    hipLaunchKernelGGL(k_boffs, dim3(1), dim3(256), 0, stream, bcnt, boffs, bcur, NB, E);
    hipLaunchKernelGGL(k_bscatter, dim3(eblk), dim3(256), 0, stream, ei_src, ei_dst, bcur, pairs, E);
    hipLaunchKernelGGL(k_agg1, dim3(NB), dim3(256), 0, stream,
                       boffs, pairs, s1, d1, h1, b1, W2, a2s, a2d, h2, s2, d2, gmax1, gmax2, N);
    hipLaunchKernelGGL(k_agg2, dim3(NB), dim3(256), 0, stream,
                       boffs, pairs, s2, d2, h2, b2, Wl1, bl1, Wl2, bl2, gmax2, (float*)d_out, N);
}

// Round 6
// 466.490 us; speedup vs baseline: 2.1634x; 2.1634x over previous
//
#include <hip/hip_runtime.h>

// GAT (2 layers, heads=1) + 2-layer MLP head. N=100000, E=3200000, D=128.
// R6: bucket scatter + per-block LDS counting sort -> per-node runs ->
// REGISTER-accumulated gather aggregation (no atomics in hot loop),
// 4-way unrolled independent chains. Fused epilogues as before.
// Softmax stabilization uses a GLOBAL upper bound m̄_i = leaky(gmax_asrc + adst_i)
// (valid since leaky_relu is monotone); alpha is mathematically unchanged.

#define NEG 0.2f
#define BSH 6
#define BNODES 64            // nodes per bucket
#define MAXB 1600            // >= ceil(100000/64)=1563
#define CAP 2560             // LDS edge capacity per bucket (mean 2048, +11 sigma)

__device__ __forceinline__ float lrelu(float x) { return x > 0.0f ? x : NEG * x; }

__device__ __forceinline__ unsigned fenc(float f) {
    unsigned u = __float_as_uint(f);
    return (u & 0x80000000u) ? ~u : (u | 0x80000000u);
}
__device__ __forceinline__ float fdec(unsigned e) {
    return (e & 0x80000000u) ? __uint_as_float(e & 0x7FFFFFFFu) : __uint_as_float(~e);
}

__global__ __launch_bounds__(256) void k_init(unsigned* g, int* bcnt, int NB) {
    int i = blockIdx.x * 256 + threadIdx.x;
    if (i < NB) bcnt[i] = 0;
    if (i < 2) g[i] = 0u;
}

// K1: h1 = x @ W1 (128->16), s1 = h1·a1s, d1 = h1·a1d, gmax1 = max(s1)
__global__ __launch_bounds__(256) void k_gemm1(
    const float* __restrict__ x, const float* __restrict__ W1,
    const float* __restrict__ a1s, const float* __restrict__ a1d,
    float* __restrict__ h1, float* __restrict__ s1, float* __restrict__ d1,
    unsigned* __restrict__ gmax, int N)
{
    __shared__ float sW[128 * 16];
    __shared__ float sx[64 * 132];
    __shared__ float wm[4];
    int tid = threadIdx.x;
    for (int i = tid; i < 2048; i += 256) sW[i] = W1[i];
    int node0 = blockIdx.x * 64;
    for (int i = tid; i < 64 * 32; i += 256) {
        int row = i >> 5, c4 = i & 31;
        int n = node0 + row;
        float4 v = make_float4(0.f, 0.f, 0.f, 0.f);
        if (n < N) v = ((const float4*)x)[(size_t)n * 32 + c4];
        *(float4*)&sx[row * 132 + c4 * 4] = v;
    }
    __syncthreads();

    int node = node0 + (tid >> 2);
    int grp  = tid & 3;
    const float* xr = &sx[(tid >> 2) * 132];
    float4 acc = make_float4(0.f, 0.f, 0.f, 0.f);
#pragma unroll 8
    for (int j = 0; j < 128; ++j) {
        float xv = xr[j];
        float4 w = *(const float4*)&sW[j * 16 + grp * 4];
        acc.x += xv * w.x; acc.y += xv * w.y; acc.z += xv * w.z; acc.w += xv * w.w;
    }
    float4 as = ((const float4*)a1s)[grp];
    float4 ad = ((const float4*)a1d)[grp];
    float sv = acc.x * as.x + acc.y * as.y + acc.z * as.z + acc.w * as.w;
    float dv = acc.x * ad.x + acc.y * ad.y + acc.z * ad.z + acc.w * ad.w;
    sv += __shfl_xor(sv, 1); sv += __shfl_xor(sv, 2);
    dv += __shfl_xor(dv, 1); dv += __shfl_xor(dv, 2);
    if (node < N) {
        *(float4*)&h1[(size_t)node * 16 + grp * 4] = acc;
        if (grp == 0) { s1[node] = sv; d1[node] = dv; }
    }
    float m = (node < N) ? sv : -3.4e38f;
#pragma unroll
    for (int off = 32; off >= 1; off >>= 1) m = fmaxf(m, __shfl_xor(m, off));
    if ((tid & 63) == 0) wm[tid >> 6] = m;
    __syncthreads();
    if (tid == 0) {
        float b = fmaxf(fmaxf(wm[0], wm[1]), fmaxf(wm[2], wm[3]));
        atomicMax(gmax, fenc(b));
    }
}

// bucket histogram, LDS-aggregated
__global__ __launch_bounds__(256) void k_bcount(const int* __restrict__ edst,
                                                int* __restrict__ bcnt, int E, int NB) {
    __shared__ int lc[MAXB];
    int tid = threadIdx.x;
    for (int i = tid; i < NB; i += 256) lc[i] = 0;
    __syncthreads();
    int stride = gridDim.x * 256;
    for (int e = blockIdx.x * 256 + tid; e < E; e += stride)
        atomicAdd(&lc[edst[e] >> BSH], 1);
    __syncthreads();
    for (int i = tid; i < NB; i += 256) { int v = lc[i]; if (v) atomicAdd(&bcnt[i], v); }
}

// exclusive scan of bucket counts -> boffs[NB+1]; init padded cursors
__global__ __launch_bounds__(256) void k_boffs(const int* __restrict__ bcnt,
                                               int* __restrict__ boffs, int* __restrict__ bcur,
                                               int NB, int E) {
    __shared__ int l[MAXB + 1];
    int tid = threadIdx.x;
    for (int i = tid; i < NB; i += 256) l[i] = bcnt[i];
    __syncthreads();
    if (tid == 0) { int run = 0; for (int i = 0; i < NB; ++i) { int c = l[i]; l[i] = run; run += c; } l[NB] = run; }
    __syncthreads();
    for (int i = tid; i < NB; i += 256) { boffs[i] = l[i]; bcur[i * 16] = l[i]; }
    if (tid == 0) boffs[NB] = E;
}

// scatter packed (dstlow<<17 | src) into bucket regions
__global__ __launch_bounds__(256) void k_bscatter(const int* __restrict__ esrc,
                                                  const int* __restrict__ edst,
                                                  int* __restrict__ bcur,
                                                  unsigned* __restrict__ pairs, int E) {
    int e = blockIdx.x * 256 + threadIdx.x;
    if (e >= E) return;
    int d = edst[e], s = esrc[e];
    int pos = atomicAdd(&bcur[(d >> BSH) * 16], 1);
    pairs[pos] = ((unsigned)(d & (BNODES - 1)) << 17) | (unsigned)s;
}

// ---- layer-1 aggregation (LDS sort + register acc) + norm/bias/relu + L2 GEMM/scores ----
__global__ __launch_bounds__(256) void k_agg1(
    const int* __restrict__ boffs, const unsigned* __restrict__ pairs,
    const float* __restrict__ s1, const float* __restrict__ d1, const float* __restrict__ h1,
    const float* __restrict__ b1, const float* __restrict__ W2,
    const float* __restrict__ a2s, const float* __restrict__ a2d,
    float* __restrict__ h2, float* __restrict__ s2, float* __restrict__ d2,
    const unsigned* __restrict__ gmax1p, unsigned* __restrict__ gmax2, int N)
{
    __shared__ unsigned raw[CAP];
    __shared__ unsigned srt[CAP];
    __shared__ int lcnt[BNODES];          // histogram -> cursors
    __shared__ int lofs[BNODES + 1];      // run boundaries
    __shared__ float dds[BNODES], mbs[BNODES];
    __shared__ float sW[160], sb[16], sas[16], sad[16];
    __shared__ float wm[4];
    float* accF = (float*)raw;            // fallback accumulators (64*17 floats)

    int tid = threadIdx.x;
    if (tid < 160) sW[tid] = W2[tid];
    if (tid < 16) {
        sb[tid]  = b1[tid];
        sas[tid] = (tid < 10) ? a2s[tid] : 0.f;
        sad[tid] = (tid < 10) ? a2d[tid] : 0.f;
    }
    int node0 = blockIdx.x << BSH;
    float g0 = fdec(*gmax1p);
    if (tid < BNODES) {
        int n = node0 + tid;
        float dd = (n < N) ? d1[n] : 0.f;
        dds[tid] = dd; mbs[tid] = lrelu(g0 + dd);
        lcnt[tid] = 0;
    }
    __syncthreads();

    int jbeg = boffs[blockIdx.x], jend = boffs[blockIdx.x + 1];
    int cnt = jend - jbeg;
    int g = tid >> 4, k = tid & 15;

    // self-loop register init
    float accv[4], denv[4];
#pragma unroll
    for (int qq = 0; qq < 4; ++qq) {
        int nl = g * 4 + qq, n = node0 + nl;
        float w = (n < N) ? __expf(lrelu(s1[n] + dds[nl]) - mbs[nl]) : 0.f;
        accv[qq] = (n < N) ? w * h1[(size_t)n * 16 + k] : 0.f;
        denv[qq] = w;
    }

    if (cnt <= CAP) {                     // block-uniform branch
        // A: load + histogram
        for (int i = tid; i < cnt; i += 256) {
            unsigned p = pairs[jbeg + i];
            raw[i] = p;
            atomicAdd(&lcnt[p >> 17], 1);
        }
        __syncthreads();
        // B: 64-lane scan (wave 0)
        if (tid < 64) {
            int c = lcnt[tid], pfx = c;
#pragma unroll
            for (int off = 1; off < 64; off <<= 1) {
                int t = __shfl_up(pfx, off, 64);
                if (tid >= off) pfx += t;
            }
            lofs[tid + 1] = pfx;
            if (tid == 0) lofs[0] = 0;
            lcnt[tid] = pfx - c;          // exclusive -> cursor
        }
        __syncthreads();
        // C: LDS scatter -> dst-sorted src list
        for (int i = tid; i < cnt; i += 256) {
            unsigned p = raw[i];
            int pos = atomicAdd(&lcnt[p >> 17], 1);
            srt[pos] = p & 0x1FFFF;
        }
        __syncthreads();
        // D: per-node runs, register accumulation, 4-way unrolled chains
#pragma unroll
        for (int qq = 0; qq < 4; ++qq) {
            int nl = g * 4 + qq;
            float dd = dds[nl], mb = mbs[nl];
            int j = lofs[nl], j1 = lofs[nl + 1];
            float a = accv[qq], dn = denv[qq];
            for (; j + 4 <= j1; j += 4) {
                int e0 = srt[j], e1 = srt[j + 1], e2 = srt[j + 2], e3 = srt[j + 3];
                float v0 = s1[e0], v1 = s1[e1], v2 = s1[e2], v3 = s1[e3];
                float h0 = h1[(size_t)e0 * 16 + k], h1v = h1[(size_t)e1 * 16 + k];
                float h2v = h1[(size_t)e2 * 16 + k], h3v = h1[(size_t)e3 * 16 + k];
                float w0 = __expf(lrelu(v0 + dd) - mb), w1 = __expf(lrelu(v1 + dd) - mb);
                float w2 = __expf(lrelu(v2 + dd) - mb), w3 = __expf(lrelu(v3 + dd) - mb);
                a += w0 * h0 + w1 * h1v + w2 * h2v + w3 * h3v;
                dn += (w0 + w1) + (w2 + w3);
            }
            for (; j < j1; ++j) {
                int e0 = srt[j];
                float w0 = __expf(lrelu(s1[e0] + dd) - mb);
                a += w0 * h1[(size_t)e0 * 16 + k]; dn += w0;
            }
            accv[qq] = a; denv[qq] = dn;
        }
    } else {
        // fallback (never triggers for uniform-random dst; kept for correctness)
        for (int i = tid; i < BNODES * 17; i += 256) accF[i] = 0.f;
        __syncthreads();
        for (int j = jbeg + tid; j < jend; j += 256) {
            unsigned p = pairs[j];
            int src = p & 0x1FFFF, nl = p >> 17;
            float w = __expf(lrelu(s1[src] + dds[nl]) - mbs[nl]);
#pragma unroll
            for (int kk = 0; kk < 16; ++kk)
                atomicAdd(&accF[nl * 17 + kk], w * h1[(size_t)src * 16 + kk]);
            atomicAdd(&accF[nl * 17 + 16], w);
        }
        __syncthreads();
#pragma unroll
        for (int qq = 0; qq < 4; ++qq) {
            int nl = g * 4 + qq;
            accv[qq] += accF[nl * 17 + k];
            denv[qq] += accF[nl * 17 + 16];
        }
    }

    // fused epilogue: normalize+bias+relu, 16->10 GEMM, scores, gmax2
    float sval = -3.4e38f;
#pragma unroll
    for (int qq = 0; qq < 4; ++qq) {
        int nl = g * 4 + qq, n = node0 + nl;
        if (n >= N) continue;             // group-uniform
        float inv = 1.f / denv[qq];
        float o = fmaxf(accv[qq] * inv + sb[k], 0.f);
        float hh = 0.f;
#pragma unroll
        for (int kk = 0; kk < 16; ++kk) {
            float ov = __shfl(o, kk, 16);
            if (k < 10) hh += ov * sW[kk * 10 + k];
        }
        if (k >= 10) hh = 0.f;
        float ts = hh * sas[k];
        float td = hh * sad[k];
#pragma unroll
        for (int off = 1; off < 16; off <<= 1) {
            ts += __shfl_xor(ts, off, 16);
            td += __shfl_xor(td, off, 16);
        }
        h2[(size_t)n * 16 + k] = hh;      // zero-padded cols 10..15
        if (k == 0) { s2[n] = ts; d2[n] = td; }
        sval = fmaxf(sval, ts);
    }
    float m = sval;
#pragma unroll
    for (int off = 32; off >= 1; off >>= 1) m = fmaxf(m, __shfl_xor(m, off));
    if ((tid & 63) == 0) wm[tid >> 6] = m;
    __syncthreads();
    if (tid == 0)
        atomicMax(gmax2, fenc(fmaxf(fmaxf(wm[0], wm[1]), fmaxf(wm[2], wm[3]))));
}

// ---- layer-2 aggregation (same structure) + norm/bias + MLP head -> out ----
__global__ __launch_bounds__(256) void k_agg2(
    const int* __restrict__ boffs, const unsigned* __restrict__ pairs,
    const float* __restrict__ s2, const float* __restrict__ d2, const float* __restrict__ h2,
    const float* __restrict__ b2, const float* __restrict__ Wl1, const float* __restrict__ bl1,
    const float* __restrict__ Wl2, const float* __restrict__ bl2,
    const unsigned* __restrict__ gmax2p, float* __restrict__ out, int N)
{
    __shared__ unsigned raw[CAP];
    __shared__ unsigned srt[CAP];
    __shared__ int lcnt[BNODES];
    __shared__ int lofs[BNODES + 1];
    __shared__ float dds[BNODES], mbs[BNODES];
    __shared__ float sW1[100], sb1[16], sW2[16], sb2g[16];
    __shared__ float sbl2;
    float* accF = (float*)raw;

    int tid = threadIdx.x;
    if (tid < 100) sW1[tid] = Wl1[tid];
    if (tid < 16) {
        sb1[tid]  = (tid < 10) ? bl1[tid] : 0.f;
        sW2[tid]  = (tid < 10) ? Wl2[tid] : 0.f;
        sb2g[tid] = (tid < 10) ? b2[tid]  : 0.f;
    }
    if (tid == 0) sbl2 = bl2[0];
    int node0 = blockIdx.x << BSH;
    float g0 = fdec(*gmax2p);
    if (tid < BNODES) {
        int n = node0 + tid;
        float dd = (n < N) ? d2[n] : 0.f;
        dds[tid] = dd; mbs[tid] = lrelu(g0 + dd);
        lcnt[tid] = 0;
    }
    __syncthreads();

    int jbeg = boffs[blockIdx.x], jend = boffs[blockIdx.x + 1];
    int cnt = jend - jbeg;
    int g = tid >> 4, k = tid & 15;

    float accv[4], denv[4];
#pragma unroll
    for (int qq = 0; qq < 4; ++qq) {
        int nl = g * 4 + qq, n = node0 + nl;
        float w = (n < N) ? __expf(lrelu(s2[n] + dds[nl]) - mbs[nl]) : 0.f;
        accv[qq] = (n < N) ? w * h2[(size_t)n * 16 + k] : 0.f;   // zero-padded
        denv[qq] = w;
    }

    if (cnt <= CAP) {
        for (int i = tid; i < cnt; i += 256) {
            unsigned p = pairs[jbeg + i];
            raw[i] = p;
            atomicAdd(&lcnt[p >> 17], 1);
        }
        __syncthreads();
        if (tid < 64) {
            int c = lcnt[tid], pfx = c;
#pragma unroll
            for (int off = 1; off < 64; off <<= 1) {
                int t = __shfl_up(pfx, off, 64);
                if (tid >= off) pfx += t;
            }
            lofs[tid + 1] = pfx;
            if (tid == 0) lofs[0] = 0;
            lcnt[tid] = pfx - c;
        }
        __syncthreads();
        for (int i = tid; i < cnt; i += 256) {
            unsigned p = raw[i];
            int pos = atomicAdd(&lcnt[p >> 17], 1);
            srt[pos] = p & 0x1FFFF;
        }
        __syncthreads();
#pragma unroll
        for (int qq = 0; qq < 4; ++qq) {
            int nl = g * 4 + qq;
            float dd = dds[nl], mb = mbs[nl];
            int j = lofs[nl], j1 = lofs[nl + 1];
            float a = accv[qq], dn = denv[qq];
            for (; j + 4 <= j1; j += 4) {
                int e0 = srt[j], e1 = srt[j + 1], e2 = srt[j + 2], e3 = srt[j + 3];
                float v0 = s2[e0], v1 = s2[e1], v2 = s2[e2], v3 = s2[e3];
                float h0 = h2[(size_t)e0 * 16 + k], h1v = h2[(size_t)e1 * 16 + k];
                float h2v = h2[(size_t)e2 * 16 + k], h3v = h2[(size_t)e3 * 16 + k];
                float w0 = __expf(lrelu(v0 + dd) - mb), w1 = __expf(lrelu(v1 + dd) - mb);
                float w2 = __expf(lrelu(v2 + dd) - mb), w3 = __expf(lrelu(v3 + dd) - mb);
                a += w0 * h0 + w1 * h1v + w2 * h2v + w3 * h3v;
                dn += (w0 + w1) + (w2 + w3);
            }
            for (; j < j1; ++j) {
                int e0 = srt[j];
                float w0 = __expf(lrelu(s2[e0] + dd) - mb);
                a += w0 * h2[(size_t)e0 * 16 + k]; dn += w0;
            }
            accv[qq] = a; denv[qq] = dn;
        }
    } else {
        for (int i = tid; i < BNODES * 17; i += 256) accF[i] = 0.f;
        __syncthreads();
        for (int j = jbeg + tid; j < jend; j += 256) {
            unsigned p = pairs[j];
            int src = p & 0x1FFFF, nl = p >> 17;
            float w = __expf(lrelu(s2[src] + dds[nl]) - mbs[nl]);
#pragma unroll
            for (int kk = 0; kk < 16; ++kk)
                atomicAdd(&accF[nl * 17 + kk], w * h2[(size_t)src * 16 + kk]);
            atomicAdd(&accF[nl * 17 + 16], w);
        }
        __syncthreads();
#pragma unroll
        for (int qq = 0; qq < 4; ++qq) {
            int nl = g * 4 + qq;
            accv[qq] += accF[nl * 17 + k];
            denv[qq] += accF[nl * 17 + 16];
        }
    }

    // epilogue: normalize+bias, MLP (10->10 relu ->1) -> out
    bool fk = k < 10;
#pragma unroll
    for (int qq = 0; qq < 4; ++qq) {
        int nl = g * 4 + qq, n = node0 + nl;
        if (n >= N) continue;             // group-uniform
        float inv = 1.f / denv[qq];
        float o = fk ? accv[qq] * inv + sb2g[k] : 0.f;
        float v = sb1[k];
#pragma unroll
        for (int kk = 0; kk < 10; ++kk) {
            float ov = __shfl(o, kk, 16);
            if (fk) v += ov * sW1[kk * 10 + k];
        }
        float t = fmaxf(v, 0.f);
        float c = t * sW2[k];             // zero for k>=10
#pragma unroll
        for (int off = 1; off < 16; off <<= 1) c += __shfl_xor(c, off, 16);
        if (k == 0) out[n] = c + sbl2;
    }
}

extern "C" void kernel_launch(void* const* d_in, const int* in_sizes, int n_in,
                              void* d_out, int out_size, void* d_ws, size_t ws_size,
                              hipStream_t stream)
{
    const float* x   = (const float*)d_in[0];
    const int*   ei  = (const int*)  d_in[1];   // [2][E] int32
    const float* W1  = (const float*)d_in[2];
    const float* a1s = (const float*)d_in[3];
    const float* a1d = (const float*)d_in[4];
    const float* b1  = (const float*)d_in[5];
    const float* W2  = (const float*)d_in[6];
    const float* a2s = (const float*)d_in[7];
    const float* a2d = (const float*)d_in[8];
    const float* b2  = (const float*)d_in[9];
    const float* Wl1 = (const float*)d_in[10];
    const float* bl1 = (const float*)d_in[11];
    const float* Wl2 = (const float*)d_in[12];
    const float* bl2 = (const float*)d_in[13];

    int N = in_sizes[0] / 128;
    int E = in_sizes[1] / 2;
    const int* ei_src = ei;
    const int* ei_dst = ei + E;
    int NB = (N + BNODES - 1) >> BSH;       // 1563 for N=100000

    size_t Np = ((size_t)N + 3) & ~(size_t)3;
    size_t N16 = Np * 16;
    size_t need_bytes = (16 + Np * 36) * 4 + ((size_t)NB * 18 + 1) * 4 + (size_t)E * 4;
    if (ws_size < need_bytes) return;  // degrade to wrong-answer, never fault

    float*    ws    = (float*)d_ws;
    unsigned* gmax1 = (unsigned*)d_ws;       // [0]
    unsigned* gmax2 = gmax1 + 1;             // [1]
    float* h1 = ws + 16;                     // Np*16
    float* s1 = h1 + N16;                    // Np
    float* d1 = s1 + Np;                     // Np
    float* h2 = d1 + Np;                     // Np*16 (cols 10..15 zero)
    float* s2 = h2 + N16;                    // Np
    float* d2 = s2 + Np;                     // Np
    int* bcnt  = (int*)(d2 + Np);            // NB
    int* boffs = bcnt + NB;                  // NB+1
    int* bcur  = boffs + NB + 1;             // NB*16 (1 cursor per 64B)
    unsigned* pairs = (unsigned*)(bcur + (size_t)NB * 16);  // E

    int eblk = (E + 255) / 256;

    hipLaunchKernelGGL(k_init, dim3((NB + 255) / 256), dim3(256), 0, stream, gmax1, bcnt, NB);
    hipLaunchKernelGGL(k_gemm1, dim3((N + 63) / 64), dim3(256), 0, stream,
                       x, W1, a1s, a1d, h1, s1, d1, gmax1, N);
    hipLaunchKernelGGL(k_bcount, dim3(256), dim3(256), 0, stream, ei_dst, bcnt, E, NB);
    hipLaunchKernelGGL(k_boffs, dim3(1), dim3(256), 0, stream, bcnt, boffs, bcur, NB, E);
    hipLaunchKernelGGL(k_bscatter, dim3(eblk), dim3(256), 0, stream, ei_src, ei_dst, bcur, pairs, E);
    hipLaunchKernelGGL(k_agg1, dim3(NB), dim3(256), 0, stream,
                       boffs, pairs, s1, d1, h1, b1, W2, a2s, a2d, h2, s2, d2, gmax1, gmax2, N);
    hipLaunchKernelGGL(k_agg2, dim3(NB), dim3(256), 0, stream,
                       boffs, pairs, s2, d2, h2, b2, Wl1, bl1, Wl2, bl2, gmax2, (float*)d_out, N);
}

// Round 7
// 454.849 us; speedup vs baseline: 2.2187x; 1.0256x over previous
//
#include <hip/hip_runtime.h>

// GAT (2 layers, heads=1) + 2-layer MLP head. N=100000, E=3200000, D=128.
// R7: line-friendly COARSE split (98 buckets of 1024 nodes, LDS-sorted tiles,
// run-granular flushes) replaces the 4B fine scatter (161MB write amp).
// Agg blocks filter their 64-node fine bucket out of the coarse region
// (XCD-swizzled for L2 reuse), then LDS counting sort -> register-acc gather.
// Softmax stabilization uses a GLOBAL upper bound m̄_i = leaky(gmax_asrc + adst_i)
// (valid since leaky_relu is monotone); alpha is mathematically unchanged.

#define NEG 0.2f
#define CSH 10
#define CNODES 1024          // nodes per coarse bucket
#define NCMAX 128            // >= ceil(100000/1024)=98
#define FSH 6
#define BNODES 64            // nodes per fine bucket
#define CAP 2560             // fine-bucket edge capacity (mean 2048, +11 sigma)
#define TILE 8192            // edges per csplit block

__device__ __forceinline__ float lrelu(float x) { return x > 0.0f ? x : NEG * x; }

__device__ __forceinline__ unsigned fenc(float f) {
    unsigned u = __float_as_uint(f);
    return (u & 0x80000000u) ? ~u : (u | 0x80000000u);
}
__device__ __forceinline__ float fdec(unsigned e) {
    return (e & 0x80000000u) ? __uint_as_float(e & 0x7FFFFFFFu) : __uint_as_float(~e);
}

__global__ __launch_bounds__(256) void k_init(unsigned* g, int* chist, int NC) {
    int i = blockIdx.x * 256 + threadIdx.x;
    if (i < NC) chist[i] = 0;
    if (i < 2) g[i] = 0u;
}

// K1: h1 = x @ W1 (128->16), s1 = h1·a1s, d1 = h1·a1d, gmax1 = max(s1)
__global__ __launch_bounds__(256) void k_gemm1(
    const float* __restrict__ x, const float* __restrict__ W1,
    const float* __restrict__ a1s, const float* __restrict__ a1d,
    float* __restrict__ h1, float* __restrict__ s1, float* __restrict__ d1,
    unsigned* __restrict__ gmax, int N)
{
    __shared__ float sW[128 * 16];
    __shared__ float sx[64 * 132];
    __shared__ float wm[4];
    int tid = threadIdx.x;
    for (int i = tid; i < 2048; i += 256) sW[i] = W1[i];
    int node0 = blockIdx.x * 64;
    for (int i = tid; i < 64 * 32; i += 256) {
        int row = i >> 5, c4 = i & 31;
        int n = node0 + row;
        float4 v = make_float4(0.f, 0.f, 0.f, 0.f);
        if (n < N) v = ((const float4*)x)[(size_t)n * 32 + c4];
        *(float4*)&sx[row * 132 + c4 * 4] = v;
    }
    __syncthreads();

    int node = node0 + (tid >> 2);
    int grp  = tid & 3;
    const float* xr = &sx[(tid >> 2) * 132];
    float4 acc = make_float4(0.f, 0.f, 0.f, 0.f);
#pragma unroll 8
    for (int j = 0; j < 128; ++j) {
        float xv = xr[j];
        float4 w = *(const float4*)&sW[j * 16 + grp * 4];
        acc.x += xv * w.x; acc.y += xv * w.y; acc.z += xv * w.z; acc.w += xv * w.w;
    }
    float4 as = ((const float4*)a1s)[grp];
    float4 ad = ((const float4*)a1d)[grp];
    float sv = acc.x * as.x + acc.y * as.y + acc.z * as.z + acc.w * as.w;
    float dv = acc.x * ad.x + acc.y * ad.y + acc.z * ad.z + acc.w * ad.w;
    sv += __shfl_xor(sv, 1); sv += __shfl_xor(sv, 2);
    dv += __shfl_xor(dv, 1); dv += __shfl_xor(dv, 2);
    if (node < N) {
        *(float4*)&h1[(size_t)node * 16 + grp * 4] = acc;
        if (grp == 0) { s1[node] = sv; d1[node] = dv; }
    }
    float m = (node < N) ? sv : -3.4e38f;
#pragma unroll
    for (int off = 32; off >= 1; off >>= 1) m = fmaxf(m, __shfl_xor(m, off));
    if ((tid & 63) == 0) wm[tid >> 6] = m;
    __syncthreads();
    if (tid == 0) {
        float b = fmaxf(fmaxf(wm[0], wm[1]), fmaxf(wm[2], wm[3]));
        atomicMax(gmax, fenc(b));
    }
}

// coarse histogram, LDS-aggregated
__global__ __launch_bounds__(256) void k_chist(const int* __restrict__ edst,
                                               int* __restrict__ chist, int E, int NC) {
    __shared__ int lc[NCMAX];
    int tid = threadIdx.x;
    for (int i = tid; i < NC; i += 256) lc[i] = 0;
    __syncthreads();
    int stride = gridDim.x * 256;
    for (int e = blockIdx.x * 256 + tid; e < E; e += stride)
        atomicAdd(&lc[edst[e] >> CSH], 1);
    __syncthreads();
    for (int i = tid; i < NC; i += 256) { int v = lc[i]; if (v) atomicAdd(&chist[i], v); }
}

// scan coarse counts -> cboffs[NC+1]; init padded cursors
__global__ void k_cboffs(const int* __restrict__ chist, int* __restrict__ cboffs,
                         int* __restrict__ ccur, int NC, int E) {
    if (threadIdx.x == 0) {
        int run = 0;
        for (int c = 0; c < NC; ++c) { cboffs[c] = run; ccur[c * 16] = run; run += chist[c]; }
        cboffs[NC] = E;
    }
}

// coarse split: LDS-sort a tile of 8192 edges by coarse bucket, flush run-granular
__global__ __launch_bounds__(256) void k_csplit(
    const int* __restrict__ esrc, const int* __restrict__ edst,
    int* __restrict__ ccur, unsigned* __restrict__ pairs, int E, int NC)
{
    __shared__ unsigned lsrt[TILE];
    __shared__ int lhist[NCMAX];        // counts -> cursors
    __shared__ int lofs[NCMAX + 1];
    __shared__ int gbase[NCMAX];
    int tid = threadIdx.x;
    int base = blockIdx.x * TILE;
    int tcnt = min(TILE, E - base);
    for (int i = tid; i < NC; i += 256) lhist[i] = 0;
    __syncthreads();
    for (int i = tid; i < tcnt; i += 256)
        atomicAdd(&lhist[edst[base + i] >> CSH], 1);
    __syncthreads();
    if (tid == 0) {
        int run = 0;
        for (int c = 0; c < NC; ++c) { int v = lhist[c]; lofs[c] = run; run += v; }
        lofs[NC] = run;
    }
    __syncthreads();
    if (tid < NC) {
        int cnt = lofs[tid + 1] - lofs[tid];
        gbase[tid] = cnt ? atomicAdd(&ccur[tid * 16], cnt) : 0;
        lhist[tid] = lofs[tid];         // cursor
    }
    __syncthreads();
    for (int i = tid; i < tcnt; i += 256) {
        int e = base + i;
        int d = edst[e], s = esrc[e];
        int pos = atomicAdd(&lhist[d >> CSH], 1);
        lsrt[pos] = ((unsigned)(d & (CNODES - 1)) << 17) | (unsigned)s;
    }
    __syncthreads();
    // flattened flush: binary search for run id, coalesced run-contiguous stores
    for (int i = tid; i < tcnt; i += 256) {
        int lo = 0, hi = NC - 1;
        while (lo < hi) { int mid = (lo + hi + 1) >> 1; if (lofs[mid] <= i) lo = mid; else hi = mid - 1; }
        pairs[gbase[lo] + (i - lofs[lo])] = lsrt[i];
    }
}

// ---- layer-1 agg: filter fine bucket from coarse region, LDS sort, register acc ----
__global__ __launch_bounds__(256) void k_agg1(
    const int* __restrict__ cboffs, const unsigned* __restrict__ pairs,
    const float* __restrict__ s1, const float* __restrict__ d1, const float* __restrict__ h1,
    const float* __restrict__ b1, const float* __restrict__ W2,
    const float* __restrict__ a2s, const float* __restrict__ a2d,
    float* __restrict__ h2, float* __restrict__ s2, float* __restrict__ d2,
    const unsigned* __restrict__ gmax1p, unsigned* __restrict__ gmax2, int N, int NB, int S)
{
    __shared__ unsigned srt[CAP];
    __shared__ int lcnt[BNODES];
    __shared__ int lofs[BNODES + 1];
    __shared__ float dds[BNODES], mbs[BNODES];
    __shared__ float sW[160], sb[16], sas[16], sad[16];
    __shared__ float wm[4];
    float* accF = (float*)srt;          // fallback accumulators (64*17 <= CAP)

    int tid = threadIdx.x;
    // XCD swizzle: blocks resident on one XCD get consecutive fine buckets
    int fb = (blockIdx.x >> 3) + (blockIdx.x & 7) * S;
    if (fb >= NB) return;               // whole block exits together

    if (tid < 160) sW[tid] = W2[tid];
    if (tid < 16) {
        sb[tid]  = b1[tid];
        sas[tid] = (tid < 10) ? a2s[tid] : 0.f;
        sad[tid] = (tid < 10) ? a2d[tid] : 0.f;
    }
    int node0 = fb << FSH;
    float g0 = fdec(*gmax1p);
    if (tid < BNODES) {
        int n = node0 + tid;
        float dd = (n < N) ? d1[n] : 0.f;
        dds[tid] = dd; mbs[tid] = lrelu(g0 + dd);
        lcnt[tid] = 0;
    }
    __syncthreads();

    int cb = fb >> 4;
    unsigned fic = (unsigned)(fb & 15);
    int cbeg = cboffs[cb], cend = cboffs[cb + 1];
    int g = tid >> 4, k = tid & 15;

    // self-loop register init
    float accv[4], denv[4];
#pragma unroll
    for (int qq = 0; qq < 4; ++qq) {
        int nl = g * 4 + qq, n = node0 + nl;
        float w = (n < N) ? __expf(lrelu(s1[n] + dds[nl]) - mbs[nl]) : 0.f;
        accv[qq] = (n < N) ? w * h1[(size_t)n * 16 + k] : 0.f;
        denv[qq] = w;
    }

    // count pass (filter coarse region)
    for (int i = cbeg + tid; i < cend; i += 256) {
        unsigned p = pairs[i];
        if ((p >> 23) == fic) atomicAdd(&lcnt[(p >> 17) & 63], 1);
    }
    __syncthreads();
    if (tid < 64) {
        int c = lcnt[tid], pfx = c;
#pragma unroll
        for (int off = 1; off < 64; off <<= 1) {
            int t = __shfl_up(pfx, off, 64);
            if (tid >= off) pfx += t;
        }
        lofs[tid + 1] = pfx;
        if (tid == 0) lofs[0] = 0;
        lcnt[tid] = pfx - c;            // cursors
    }
    __syncthreads();
    int total = lofs[64];

    if (total <= CAP) {
        // scatter pass: filtered srcs, dst-sorted
        for (int i = cbeg + tid; i < cend; i += 256) {
            unsigned p = pairs[i];
            if ((p >> 23) == fic) {
                int pos = atomicAdd(&lcnt[(p >> 17) & 63], 1);
                srt[pos] = p & 0x1FFFF;
            }
        }
        __syncthreads();
        // register-accumulated gather, 4-way unrolled chains
#pragma unroll
        for (int qq = 0; qq < 4; ++qq) {
            int nl = g * 4 + qq;
            float dd = dds[nl], mb = mbs[nl];
            int j = lofs[nl], j1 = lofs[nl + 1];
            float a = accv[qq], dn = denv[qq];
            for (; j + 4 <= j1; j += 4) {
                int e0 = srt[j], e1 = srt[j + 1], e2 = srt[j + 2], e3 = srt[j + 3];
                float v0 = s1[e0], v1 = s1[e1], v2 = s1[e2], v3 = s1[e3];
                float h0 = h1[(size_t)e0 * 16 + k], h1v = h1[(size_t)e1 * 16 + k];
                float h2v = h1[(size_t)e2 * 16 + k], h3v = h1[(size_t)e3 * 16 + k];
                float w0 = __expf(lrelu(v0 + dd) - mb), w1 = __expf(lrelu(v1 + dd) - mb);
                float w2 = __expf(lrelu(v2 + dd) - mb), w3 = __expf(lrelu(v3 + dd) - mb);
                a += w0 * h0 + w1 * h1v + w2 * h2v + w3 * h3v;
                dn += (w0 + w1) + (w2 + w3);
            }
            for (; j < j1; ++j) {
                int e0 = srt[j];
                float w0 = __expf(lrelu(s1[e0] + dd) - mb);
                a += w0 * h1[(size_t)e0 * 16 + k]; dn += w0;
            }
            accv[qq] = a; denv[qq] = dn;
        }
    } else {
        // fallback (statistically unreachable; kept for correctness)
        for (int i = tid; i < BNODES * 17; i += 256) accF[i] = 0.f;
        __syncthreads();
        for (int i = cbeg + tid; i < cend; i += 256) {
            unsigned p = pairs[i];
            if ((p >> 23) != fic) continue;
            int src = p & 0x1FFFF, nl = (p >> 17) & 63;
            float w = __expf(lrelu(s1[src] + dds[nl]) - mbs[nl]);
#pragma unroll
            for (int kk = 0; kk < 16; ++kk)
                atomicAdd(&accF[nl * 17 + kk], w * h1[(size_t)src * 16 + kk]);
            atomicAdd(&accF[nl * 17 + 16], w);
        }
        __syncthreads();
#pragma unroll
        for (int qq = 0; qq < 4; ++qq) {
            int nl = g * 4 + qq;
            accv[qq] += accF[nl * 17 + k];
            denv[qq] += accF[nl * 17 + 16];
        }
    }

    // fused epilogue: normalize+bias+relu, 16->10 GEMM, scores, gmax2
    float sval = -3.4e38f;
#pragma unroll
    for (int qq = 0; qq < 4; ++qq) {
        int nl = g * 4 + qq, n = node0 + nl;
        if (n >= N) continue;           // group-uniform
        float inv = 1.f / denv[qq];
        float o = fmaxf(accv[qq] * inv + sb[k], 0.f);
        float hh = 0.f;
#pragma unroll
        for (int kk = 0; kk < 16; ++kk) {
            float ov = __shfl(o, kk, 16);
            if (k < 10) hh += ov * sW[kk * 10 + k];
        }
        if (k >= 10) hh = 0.f;
        float ts = hh * sas[k];
        float td = hh * sad[k];
#pragma unroll
        for (int off = 1; off < 16; off <<= 1) {
            ts += __shfl_xor(ts, off, 16);
            td += __shfl_xor(td, off, 16);
        }
        h2[(size_t)n * 16 + k] = hh;    // zero-padded cols 10..15
        if (k == 0) { s2[n] = ts; d2[n] = td; }
        sval = fmaxf(sval, ts);
    }
    float m = sval;
#pragma unroll
    for (int off = 32; off >= 1; off >>= 1) m = fmaxf(m, __shfl_xor(m, off));
    if ((tid & 63) == 0) wm[tid >> 6] = m;
    __syncthreads();
    if (tid == 0)
        atomicMax(gmax2, fenc(fmaxf(fmaxf(wm[0], wm[1]), fmaxf(wm[2], wm[3]))));
}

// ---- layer-2 agg (same structure) + norm/bias + MLP head -> out ----
__global__ __launch_bounds__(256) void k_agg2(
    const int* __restrict__ cboffs, const unsigned* __restrict__ pairs,
    const float* __restrict__ s2, const float* __restrict__ d2, const float* __restrict__ h2,
    const float* __restrict__ b2, const float* __restrict__ Wl1, const float* __restrict__ bl1,
    const float* __restrict__ Wl2, const float* __restrict__ bl2,
    const unsigned* __restrict__ gmax2p, float* __restrict__ out, int N, int NB, int S)
{
    __shared__ unsigned srt[CAP];
    __shared__ int lcnt[BNODES];
    __shared__ int lofs[BNODES + 1];
    __shared__ float dds[BNODES], mbs[BNODES];
    __shared__ float sW1[100], sb1[16], sW2[16], sb2g[16];
    __shared__ float sbl2;
    float* accF = (float*)srt;

    int tid = threadIdx.x;
    int fb = (blockIdx.x >> 3) + (blockIdx.x & 7) * S;
    if (fb >= NB) return;

    if (tid < 100) sW1[tid] = Wl1[tid];
    if (tid < 16) {
        sb1[tid]  = (tid < 10) ? bl1[tid] : 0.f;
        sW2[tid]  = (tid < 10) ? Wl2[tid] : 0.f;
        sb2g[tid] = (tid < 10) ? b2[tid]  : 0.f;
    }
    if (tid == 0) sbl2 = bl2[0];
    int node0 = fb << FSH;
    float g0 = fdec(*gmax2p);
    if (tid < BNODES) {
        int n = node0 + tid;
        float dd = (n < N) ? d2[n] : 0.f;
        dds[tid] = dd; mbs[tid] = lrelu(g0 + dd);
        lcnt[tid] = 0;
    }
    __syncthreads();

    int cb = fb >> 4;
    unsigned fic = (unsigned)(fb & 15);
    int cbeg = cboffs[cb], cend = cboffs[cb + 1];
    int g = tid >> 4, k = tid & 15;

    float accv[4], denv[4];
#pragma unroll
    for (int qq = 0; qq < 4; ++qq) {
        int nl = g * 4 + qq, n = node0 + nl;
        float w = (n < N) ? __expf(lrelu(s2[n] + dds[nl]) - mbs[nl]) : 0.f;
        accv[qq] = (n < N) ? w * h2[(size_t)n * 16 + k] : 0.f;   // zero-padded
        denv[qq] = w;
    }

    for (int i = cbeg + tid; i < cend; i += 256) {
        unsigned p = pairs[i];
        if ((p >> 23) == fic) atomicAdd(&lcnt[(p >> 17) & 63], 1);
    }
    __syncthreads();
    if (tid < 64) {
        int c = lcnt[tid], pfx = c;
#pragma unroll
        for (int off = 1; off < 64; off <<= 1) {
            int t = __shfl_up(pfx, off, 64);
            if (tid >= off) pfx += t;
        }
        lofs[tid + 1] = pfx;
        if (tid == 0) lofs[0] = 0;
        lcnt[tid] = pfx - c;
    }
    __syncthreads();
    int total = lofs[64];

    if (total <= CAP) {
        for (int i = cbeg + tid; i < cend; i += 256) {
            unsigned p = pairs[i];
            if ((p >> 23) == fic) {
                int pos = atomicAdd(&lcnt[(p >> 17) & 63], 1);
                srt[pos] = p & 0x1FFFF;
            }
        }
        __syncthreads();
#pragma unroll
        for (int qq = 0; qq < 4; ++qq) {
            int nl = g * 4 + qq;
            float dd = dds[nl], mb = mbs[nl];
            int j = lofs[nl], j1 = lofs[nl + 1];
            float a = accv[qq], dn = denv[qq];
            for (; j + 4 <= j1; j += 4) {
                int e0 = srt[j], e1 = srt[j + 1], e2 = srt[j + 2], e3 = srt[j + 3];
                float v0 = s2[e0], v1 = s2[e1], v2 = s2[e2], v3 = s2[e3];
                float h0 = h2[(size_t)e0 * 16 + k], h1v = h2[(size_t)e1 * 16 + k];
                float h2v = h2[(size_t)e2 * 16 + k], h3v = h2[(size_t)e3 * 16 + k];
                float w0 = __expf(lrelu(v0 + dd) - mb), w1 = __expf(lrelu(v1 + dd) - mb);
                float w2 = __expf(lrelu(v2 + dd) - mb), w3 = __expf(lrelu(v3 + dd) - mb);
                a += w0 * h0 + w1 * h1v + w2 * h2v + w3 * h3v;
                dn += (w0 + w1) + (w2 + w3);
            }
            for (; j < j1; ++j) {
                int e0 = srt[j];
                float w0 = __expf(lrelu(s2[e0] + dd) - mb);
                a += w0 * h2[(size_t)e0 * 16 + k]; dn += w0;
            }
            accv[qq] = a; denv[qq] = dn;
        }
    } else {
        for (int i = tid; i < BNODES * 17; i += 256) accF[i] = 0.f;
        __syncthreads();
        for (int i = cbeg + tid; i < cend; i += 256) {
            unsigned p = pairs[i];
            if ((p >> 23) != fic) continue;
            int src = p & 0x1FFFF, nl = (p >> 17) & 63;
            float w = __expf(lrelu(s2[src] + dds[nl]) - mbs[nl]);
#pragma unroll
            for (int kk = 0; kk < 16; ++kk)
                atomicAdd(&accF[nl * 17 + kk], w * h2[(size_t)src * 16 + kk]);
            atomicAdd(&accF[nl * 17 + 16], w);
        }
        __syncthreads();
#pragma unroll
        for (int qq = 0; qq < 4; ++qq) {
            int nl = g * 4 + qq;
            accv[qq] += accF[nl * 17 + k];
            denv[qq] += accF[nl * 17 + 16];
        }
    }

    bool fk = k < 10;
#pragma unroll
    for (int qq = 0; qq < 4; ++qq) {
        int nl = g * 4 + qq, n = node0 + nl;
        if (n >= N) continue;           // group-uniform
        float inv = 1.f / denv[qq];
        float o = fk ? accv[qq] * inv + sb2g[k] : 0.f;
        float v = sb1[k];
#pragma unroll
        for (int kk = 0; kk < 10; ++kk) {
            float ov = __shfl(o, kk, 16);
            if (fk) v += ov * sW1[kk * 10 + k];
        }
        float t = fmaxf(v, 0.f);
        float c = t * sW2[k];           // zero for k>=10
#pragma unroll
        for (int off = 1; off < 16; off <<= 1) c += __shfl_xor(c, off, 16);
        if (k == 0) out[n] = c + sbl2;
    }
}

extern "C" void kernel_launch(void* const* d_in, const int* in_sizes, int n_in,
                              void* d_out, int out_size, void* d_ws, size_t ws_size,
                              hipStream_t stream)
{
    const float* x   = (const float*)d_in[0];
    const int*   ei  = (const int*)  d_in[1];   // [2][E] int32
    const float* W1  = (const float*)d_in[2];
    const float* a1s = (const float*)d_in[3];
    const float* a1d = (const float*)d_in[4];
    const float* b1  = (const float*)d_in[5];
    const float* W2  = (const float*)d_in[6];
    const float* a2s = (const float*)d_in[7];
    const float* a2d = (const float*)d_in[8];
    const float* b2  = (const float*)d_in[9];
    const float* Wl1 = (const float*)d_in[10];
    const float* bl1 = (const float*)d_in[11];
    const float* Wl2 = (const float*)d_in[12];
    const float* bl2 = (const float*)d_in[13];

    int N = in_sizes[0] / 128;
    int E = in_sizes[1] / 2;
    const int* ei_src = ei;
    const int* ei_dst = ei + E;
    int NB = (N + BNODES - 1) >> FSH;        // 1563 fine buckets
    int NC = (N + CNODES - 1) >> CSH;        // 98 coarse buckets (<= NCMAX)
    int S  = (NB + 7) / 8;                   // fine buckets per XCD slice (196)

    size_t Np = ((size_t)N + 3) & ~(size_t)3;
    size_t N16 = Np * 16;
    size_t need_bytes = (16 + Np * 36) * 4 + ((size_t)NC * 18 + 1) * 4 + (size_t)E * 4;
    if (ws_size < need_bytes) return;  // degrade to wrong-answer, never fault

    float*    ws    = (float*)d_ws;
    unsigned* gmax1 = (unsigned*)d_ws;       // [0]
    unsigned* gmax2 = gmax1 + 1;             // [1]
    float* h1 = ws + 16;                     // Np*16
    float* s1 = h1 + N16;                    // Np
    float* d1 = s1 + Np;                     // Np
    float* h2 = d1 + Np;                     // Np*16 (cols 10..15 zero)
    float* s2 = h2 + N16;                    // Np
    float* d2 = s2 + Np;                     // Np
    int* chist  = (int*)(d2 + Np);           // NC
    int* cboffs = chist + NC;                // NC+1
    int* ccur   = cboffs + NC + 1;           // NC*16 (1 cursor per 64B)
    unsigned* pairs = (unsigned*)(ccur + (size_t)NC * 16);  // E

    hipLaunchKernelGGL(k_init, dim3(1), dim3(256), 0, stream, gmax1, chist, NC);
    hipLaunchKernelGGL(k_gemm1, dim3((N + 63) / 64), dim3(256), 0, stream,
                       x, W1, a1s, a1d, h1, s1, d1, gmax1, N);
    hipLaunchKernelGGL(k_chist, dim3(256), dim3(256), 0, stream, ei_dst, chist, E, NC);
    hipLaunchKernelGGL(k_cboffs, dim3(1), dim3(64), 0, stream, chist, cboffs, ccur, NC, E);
    hipLaunchKernelGGL(k_csplit, dim3((E + TILE - 1) / TILE), dim3(256), 0, stream,
                       ei_src, ei_dst, ccur, pairs, E, NC);
    hipLaunchKernelGGL(k_agg1, dim3(8 * S), dim3(256), 0, stream,
                       cboffs, pairs, s1, d1, h1, b1, W2, a2s, a2d, h2, s2, d2,
                       gmax1, gmax2, N, NB, S);
    hipLaunchKernelGGL(k_agg2, dim3(8 * S), dim3(256), 0, stream,
                       cboffs, pairs, s2, d2, h2, b2, Wl1, bl1, Wl2, bl2,
                       gmax2, (float*)d_out, N, NB, S);
}

// Round 8
// 349.272 us; speedup vs baseline: 2.8894x; 1.3023x over previous
//
#include <hip/hip_runtime.h>

// GAT (2 layers, heads=1) + 2-layer MLP head. N=100000, E=3200000, D=128.
// R8: one-shot split to 256-node buckets (391), run-granular flushes.
// Agg blocks own their bucket: LDS counting sort -> register-acc gather with
// 4-lanes-per-node float4 h-rows (4x less exp redundancy than 16-lane).
// Softmax stabilization uses a GLOBAL upper bound m̄_i = leaky(gmax_asrc + adst_i)
// (valid since leaky_relu is monotone); alpha is mathematically unchanged.

#define NEG 0.2f
#define FSH 8
#define BNODES 256           // nodes per bucket
#define NSBMAX 512           // >= ceil(100000/256)=391
#define CAP 9216             // bucket edge capacity (mean 8192, +11 sigma)
#define TILE 8192            // edges per csplit block

__device__ __forceinline__ float lrelu(float x) { return x > 0.0f ? x : NEG * x; }

__device__ __forceinline__ unsigned fenc(float f) {
    unsigned u = __float_as_uint(f);
    return (u & 0x80000000u) ? ~u : (u | 0x80000000u);
}
__device__ __forceinline__ float fdec(unsigned e) {
    return (e & 0x80000000u) ? __uint_as_float(e & 0x7FFFFFFFu) : __uint_as_float(~e);
}

__global__ __launch_bounds__(256) void k_init(unsigned* g, int* chist, int NSB) {
    int i = blockIdx.x * 256 + threadIdx.x;
    if (i < NSB) chist[i] = 0;
    if (i < 2) g[i] = 0u;
}

// K1: h1 = x @ W1 (128->16), s1 = h1·a1s, d1 = h1·a1d, gmax1 = max(s1)
__global__ __launch_bounds__(256) void k_gemm1(
    const float* __restrict__ x, const float* __restrict__ W1,
    const float* __restrict__ a1s, const float* __restrict__ a1d,
    float* __restrict__ h1, float* __restrict__ s1, float* __restrict__ d1,
    unsigned* __restrict__ gmax, int N)
{
    __shared__ float sW[128 * 16];
    __shared__ float sx[64 * 132];
    __shared__ float wm[4];
    int tid = threadIdx.x;
    for (int i = tid; i < 2048; i += 256) sW[i] = W1[i];
    int node0 = blockIdx.x * 64;
    for (int i = tid; i < 64 * 32; i += 256) {
        int row = i >> 5, c4 = i & 31;
        int n = node0 + row;
        float4 v = make_float4(0.f, 0.f, 0.f, 0.f);
        if (n < N) v = ((const float4*)x)[(size_t)n * 32 + c4];
        *(float4*)&sx[row * 132 + c4 * 4] = v;
    }
    __syncthreads();

    int node = node0 + (tid >> 2);
    int grp  = tid & 3;
    const float* xr = &sx[(tid >> 2) * 132];
    float4 acc = make_float4(0.f, 0.f, 0.f, 0.f);
#pragma unroll 8
    for (int j = 0; j < 128; ++j) {
        float xv = xr[j];
        float4 w = *(const float4*)&sW[j * 16 + grp * 4];
        acc.x += xv * w.x; acc.y += xv * w.y; acc.z += xv * w.z; acc.w += xv * w.w;
    }
    float4 as = ((const float4*)a1s)[grp];
    float4 ad = ((const float4*)a1d)[grp];
    float sv = acc.x * as.x + acc.y * as.y + acc.z * as.z + acc.w * as.w;
    float dv = acc.x * ad.x + acc.y * ad.y + acc.z * ad.z + acc.w * ad.w;
    sv += __shfl_xor(sv, 1); sv += __shfl_xor(sv, 2);
    dv += __shfl_xor(dv, 1); dv += __shfl_xor(dv, 2);
    if (node < N) {
        *(float4*)&h1[(size_t)node * 16 + grp * 4] = acc;
        if (grp == 0) { s1[node] = sv; d1[node] = dv; }
    }
    float m = (node < N) ? sv : -3.4e38f;
#pragma unroll
    for (int off = 32; off >= 1; off >>= 1) m = fmaxf(m, __shfl_xor(m, off));
    if ((tid & 63) == 0) wm[tid >> 6] = m;
    __syncthreads();
    if (tid == 0) {
        float b = fmaxf(fmaxf(wm[0], wm[1]), fmaxf(wm[2], wm[3]));
        atomicMax(gmax, fenc(b));
    }
}

// bucket histogram (dst>>8), LDS-aggregated
__global__ __launch_bounds__(256) void k_chist(const int* __restrict__ edst,
                                               int* __restrict__ chist, int E, int NSB) {
    __shared__ int lc[NSBMAX];
    int tid = threadIdx.x;
    for (int i = tid; i < NSB; i += 256) lc[i] = 0;
    __syncthreads();
    int stride = gridDim.x * 256;
    for (int e = blockIdx.x * 256 + tid; e < E; e += stride)
        atomicAdd(&lc[edst[e] >> FSH], 1);
    __syncthreads();
    for (int i = tid; i < NSB; i += 256) { int v = lc[i]; if (v) atomicAdd(&chist[i], v); }
}

// scan bucket counts -> cboffs[NSB+1]; init padded cursors
__global__ void k_cboffs(const int* __restrict__ chist, int* __restrict__ cboffs,
                         int* __restrict__ ccur, int NSB, int E) {
    if (threadIdx.x == 0) {
        int run = 0;
        for (int c = 0; c < NSB; ++c) { cboffs[c] = run; ccur[c * 16] = run; run += chist[c]; }
        cboffs[NSB] = E;
    }
}

// split: LDS-sort a tile of 8192 edges by 256-node bucket, flush run-granular
__global__ __launch_bounds__(512) void k_csplit(
    const int* __restrict__ esrc, const int* __restrict__ edst,
    int* __restrict__ ccur, unsigned* __restrict__ pairs, int E, int NSB)
{
    __shared__ unsigned lsrt[TILE];
    __shared__ int lhist[NSBMAX];        // counts -> cursors
    __shared__ int lofs[NSBMAX + 1];
    __shared__ int gbase[NSBMAX];
    __shared__ int wsum[8];
    int tid = threadIdx.x;
    int base = blockIdx.x * TILE;
    int tcnt = min(TILE, E - base);
    for (int i = tid; i < NSB; i += 512) lhist[i] = 0;
    __syncthreads();
    for (int i = tid; i < tcnt; i += 512)
        atomicAdd(&lhist[edst[base + i] >> FSH], 1);
    __syncthreads();
    // padded 512-element scan (8 waves x 64-lane shfl + carries)
    int c = (tid < NSB) ? lhist[tid] : 0;
    int pfx = c;
#pragma unroll
    for (int off = 1; off < 64; off <<= 1) {
        int t = __shfl_up(pfx, off, 64);
        if ((tid & 63) >= off) pfx += t;
    }
    if ((tid & 63) == 63) wsum[tid >> 6] = pfx;
    __syncthreads();
    int carry = 0;
    for (int w = 0; w < (tid >> 6); ++w) carry += wsum[w];
    pfx += carry;
    if (tid < NSB) {
        lofs[tid + 1] = pfx;
        gbase[tid] = c ? atomicAdd(&ccur[tid * 16], c) : 0;
        lhist[tid] = pfx - c;            // cursor
    }
    if (tid == 0) lofs[0] = 0;
    __syncthreads();
    for (int i = tid; i < tcnt; i += 512) {
        int e = base + i;
        int d = edst[e], s = esrc[e];
        int pos = atomicAdd(&lhist[d >> FSH], 1);
        lsrt[pos] = ((unsigned)(d & (BNODES - 1)) << 17) | (unsigned)s;
    }
    __syncthreads();
    // flattened flush: binary search run id, coalesced run-contiguous stores
    for (int i = tid; i < tcnt; i += 512) {
        int lo = 0, hi = NSB - 1;
        while (lo < hi) { int mid = (lo + hi + 1) >> 1; if (lofs[mid] <= i) lo = mid; else hi = mid - 1; }
        pairs[gbase[lo] + (i - lofs[lo])] = lsrt[i];
    }
}

// ---- layer-1 agg: own-bucket LDS sort + 4-lane float4 register gather ----
__global__ __launch_bounds__(512) void k_agg1(
    const int* __restrict__ boffs, const unsigned* __restrict__ pairs,
    const float* __restrict__ s1, const float* __restrict__ d1, const float* __restrict__ h1,
    const float* __restrict__ b1, const float* __restrict__ W2,
    const float* __restrict__ a2s, const float* __restrict__ a2d,
    float* __restrict__ h2, float* __restrict__ s2, float* __restrict__ d2,
    const unsigned* __restrict__ gmax1p, unsigned* __restrict__ gmax2, int N)
{
    __shared__ unsigned srt[CAP];
    __shared__ float accs[BNODES * 17];
    __shared__ int lcnt[BNODES];
    __shared__ int lofs[BNODES + 1];
    __shared__ float dds[BNODES], mbs[BNODES];
    __shared__ float sW[160], sb[16], sas[16], sad[16];
    __shared__ int wsum[8];
    __shared__ float wm[8];

    int tid = threadIdx.x;
    int fb = blockIdx.x;
    if (tid < 160) sW[tid] = W2[tid];
    if (tid < 16) {
        sb[tid]  = b1[tid];
        sas[tid] = (tid < 10) ? a2s[tid] : 0.f;
        sad[tid] = (tid < 10) ? a2d[tid] : 0.f;
    }
    int node0 = fb << FSH;
    float g0 = fdec(*gmax1p);
    if (tid < BNODES) {
        int n = node0 + tid;
        float dd = (n < N) ? d1[n] : 0.f;
        dds[tid] = dd; mbs[tid] = lrelu(g0 + dd);
        lcnt[tid] = 0;
    }
    __syncthreads();

    int jbeg = boffs[fb], jend = boffs[fb + 1];
    int cnt = jend - jbeg;

    // count pass (own region only, coalesced, L2-hot)
    for (int i = tid; i < cnt; i += 512)
        atomicAdd(&lcnt[(pairs[jbeg + i] >> 17) & (BNODES - 1)], 1);
    __syncthreads();
    // 256-key scan (padded to 512 threads)
    int c = (tid < BNODES) ? lcnt[tid] : 0;
    int pfx = c;
#pragma unroll
    for (int off = 1; off < 64; off <<= 1) {
        int t = __shfl_up(pfx, off, 64);
        if ((tid & 63) >= off) pfx += t;
    }
    if ((tid & 63) == 63) wsum[tid >> 6] = pfx;
    __syncthreads();
    int carry = 0;
    for (int w = 0; w < (tid >> 6); ++w) carry += wsum[w];
    pfx += carry;
    if (tid < BNODES) { lofs[tid + 1] = pfx; lcnt[tid] = pfx - c; }
    if (tid == 0) lofs[0] = 0;
    __syncthreads();
    int total = lofs[BNODES];

    int gg = tid >> 2, q = tid & 3;      // 128 gather groups x 4 lanes
    float4 accv[2]; float den[2];
#pragma unroll
    for (int qq = 0; qq < 2; ++qq) {
        int nl = gg * 2 + qq, n = node0 + nl;
        if (n < N) {
            float w = __expf(lrelu(s1[n] + dds[nl]) - mbs[nl]);
            float4 hv = *(const float4*)&h1[(size_t)n * 16 + 4 * q];
            accv[qq] = make_float4(w * hv.x, w * hv.y, w * hv.z, w * hv.w);
            den[qq] = w;
        } else { accv[qq] = make_float4(0.f, 0.f, 0.f, 0.f); den[qq] = 0.f; }
    }

    if (total <= CAP) {
        // scatter pass -> dst-sorted srcs
        for (int i = tid; i < cnt; i += 512) {
            unsigned p = pairs[jbeg + i];
            int pos = atomicAdd(&lcnt[(p >> 17) & (BNODES - 1)], 1);
            srt[pos] = p & 0x1FFFF;
        }
        __syncthreads();
        // register gather: 4-way unrolled independent chains, float4 h-rows
#pragma unroll
        for (int qq = 0; qq < 2; ++qq) {
            int nl = gg * 2 + qq;
            float dd = dds[nl], mb = mbs[nl];
            int j = lofs[nl], j1 = lofs[nl + 1];
            float4 a = accv[qq]; float dn = den[qq];
            for (; j + 4 <= j1; j += 4) {
                int e0 = srt[j], e1 = srt[j + 1], e2 = srt[j + 2], e3 = srt[j + 3];
                float v0 = s1[e0], v1 = s1[e1], v2 = s1[e2], v3 = s1[e3];
                float4 H0 = *(const float4*)&h1[(size_t)e0 * 16 + 4 * q];
                float4 H1 = *(const float4*)&h1[(size_t)e1 * 16 + 4 * q];
                float4 H2 = *(const float4*)&h1[(size_t)e2 * 16 + 4 * q];
                float4 H3 = *(const float4*)&h1[(size_t)e3 * 16 + 4 * q];
                float w0 = __expf(lrelu(v0 + dd) - mb), w1 = __expf(lrelu(v1 + dd) - mb);
                float w2 = __expf(lrelu(v2 + dd) - mb), w3 = __expf(lrelu(v3 + dd) - mb);
                a.x += w0 * H0.x + w1 * H1.x + w2 * H2.x + w3 * H3.x;
                a.y += w0 * H0.y + w1 * H1.y + w2 * H2.y + w3 * H3.y;
                a.z += w0 * H0.z + w1 * H1.z + w2 * H2.z + w3 * H3.z;
                a.w += w0 * H0.w + w1 * H1.w + w2 * H2.w + w3 * H3.w;
                dn += (w0 + w1) + (w2 + w3);
            }
            for (; j < j1; ++j) {
                int e0 = srt[j];
                float w0 = __expf(lrelu(s1[e0] + dd) - mb);
                float4 H0 = *(const float4*)&h1[(size_t)e0 * 16 + 4 * q];
                a.x += w0 * H0.x; a.y += w0 * H0.y; a.z += w0 * H0.z; a.w += w0 * H0.w;
                dn += w0;
            }
            accv[qq] = a; den[qq] = dn;
        }
        __syncthreads();               // before reusing accs
    } else {
        // fallback (statistically unreachable)
        for (int i = tid; i < BNODES * 17; i += 512) accs[i] = 0.f;
        __syncthreads();
        for (int i = tid; i < cnt; i += 512) {
            unsigned p = pairs[jbeg + i];
            int src = p & 0x1FFFF, nl = (p >> 17) & (BNODES - 1);
            float w = __expf(lrelu(s1[src] + dds[nl]) - mbs[nl]);
#pragma unroll
            for (int kk = 0; kk < 4; ++kk)
                atomicAdd(&accs[nl * 17 + 4 * q + kk],
                          w * h1[(size_t)src * 16 + 4 * q + kk]);
            if (q == 0) atomicAdd(&accs[nl * 17 + 16], w);
        }
        __syncthreads();
#pragma unroll
        for (int qq = 0; qq < 2; ++qq) {
            int nl = gg * 2 + qq;
            accv[qq].x += accs[nl * 17 + 4 * q + 0];
            accv[qq].y += accs[nl * 17 + 4 * q + 1];
            accv[qq].z += accs[nl * 17 + 4 * q + 2];
            accv[qq].w += accs[nl * 17 + 4 * q + 3];
            den[qq] += accs[nl * 17 + 16];
        }
        __syncthreads();
    }

    // stage accumulators to LDS (stride-17 rows)
#pragma unroll
    for (int qq = 0; qq < 2; ++qq) {
        int nl = gg * 2 + qq;
        accs[nl * 17 + 4 * q + 0] = accv[qq].x;
        accs[nl * 17 + 4 * q + 1] = accv[qq].y;
        accs[nl * 17 + 4 * q + 2] = accv[qq].z;
        accs[nl * 17 + 4 * q + 3] = accv[qq].w;
        if (q == 0) accs[nl * 17 + 16] = den[qq];
    }
    __syncthreads();

    // epilogue: 32 groups of 16 lanes, 8 nodes each
    int g = tid >> 4, k = tid & 15;
    float sval = -3.4e38f;
#pragma unroll
    for (int qq = 0; qq < 8; ++qq) {
        int nl = g * 8 + qq, n = node0 + nl;
        if (n >= N) continue;            // group-uniform
        float inv = 1.f / accs[nl * 17 + 16];
        float o = fmaxf(accs[nl * 17 + k] * inv + sb[k], 0.f);
        float hh = 0.f;
#pragma unroll
        for (int kk = 0; kk < 16; ++kk) {
            float ov = __shfl(o, kk, 16);
            if (k < 10) hh += ov * sW[kk * 10 + k];
        }
        if (k >= 10) hh = 0.f;
        float ts = hh * sas[k];
        float td = hh * sad[k];
#pragma unroll
        for (int off = 1; off < 16; off <<= 1) {
            ts += __shfl_xor(ts, off, 16);
            td += __shfl_xor(td, off, 16);
        }
        h2[(size_t)n * 16 + k] = hh;     // zero-padded cols 10..15
        if (k == 0) { s2[n] = ts; d2[n] = td; }
        sval = fmaxf(sval, ts);
    }
    float m = sval;
#pragma unroll
    for (int off = 32; off >= 1; off >>= 1) m = fmaxf(m, __shfl_xor(m, off));
    if ((tid & 63) == 0) wm[tid >> 6] = m;
    __syncthreads();
    if (tid == 0) {
        float b = wm[0];
#pragma unroll
        for (int i = 1; i < 8; ++i) b = fmaxf(b, wm[i]);
        atomicMax(gmax2, fenc(b));
    }
}

// ---- layer-2 agg (same structure) + norm/bias + MLP head -> out ----
__global__ __launch_bounds__(512) void k_agg2(
    const int* __restrict__ boffs, const unsigned* __restrict__ pairs,
    const float* __restrict__ s2, const float* __restrict__ d2, const float* __restrict__ h2,
    const float* __restrict__ b2, const float* __restrict__ Wl1, const float* __restrict__ bl1,
    const float* __restrict__ Wl2, const float* __restrict__ bl2,
    const unsigned* __restrict__ gmax2p, float* __restrict__ out, int N)
{
    __shared__ unsigned srt[CAP];
    __shared__ float accs[BNODES * 17];
    __shared__ int lcnt[BNODES];
    __shared__ int lofs[BNODES + 1];
    __shared__ float dds[BNODES], mbs[BNODES];
    __shared__ float sW1[100], sb1[16], sW2[16], sb2g[16];
    __shared__ float sbl2;
    __shared__ int wsum[8];

    int tid = threadIdx.x;
    int fb = blockIdx.x;
    if (tid < 100) sW1[tid] = Wl1[tid];
    if (tid < 16) {
        sb1[tid]  = (tid < 10) ? bl1[tid] : 0.f;
        sW2[tid]  = (tid < 10) ? Wl2[tid] : 0.f;
        sb2g[tid] = (tid < 10) ? b2[tid]  : 0.f;
    }
    if (tid == 0) sbl2 = bl2[0];
    int node0 = fb << FSH;
    float g0 = fdec(*gmax2p);
    if (tid < BNODES) {
        int n = node0 + tid;
        float dd = (n < N) ? d2[n] : 0.f;
        dds[tid] = dd; mbs[tid] = lrelu(g0 + dd);
        lcnt[tid] = 0;
    }
    __syncthreads();

    int jbeg = boffs[fb], jend = boffs[fb + 1];
    int cnt = jend - jbeg;

    for (int i = tid; i < cnt; i += 512)
        atomicAdd(&lcnt[(pairs[jbeg + i] >> 17) & (BNODES - 1)], 1);
    __syncthreads();
    int c = (tid < BNODES) ? lcnt[tid] : 0;
    int pfx = c;
#pragma unroll
    for (int off = 1; off < 64; off <<= 1) {
        int t = __shfl_up(pfx, off, 64);
        if ((tid & 63) >= off) pfx += t;
    }
    if ((tid & 63) == 63) wsum[tid >> 6] = pfx;
    __syncthreads();
    int carry = 0;
    for (int w = 0; w < (tid >> 6); ++w) carry += wsum[w];
    pfx += carry;
    if (tid < BNODES) { lofs[tid + 1] = pfx; lcnt[tid] = pfx - c; }
    if (tid == 0) lofs[0] = 0;
    __syncthreads();
    int total = lofs[BNODES];

    int gg = tid >> 2, q = tid & 3;
    float4 accv[2]; float den[2];
#pragma unroll
    for (int qq = 0; qq < 2; ++qq) {
        int nl = gg * 2 + qq, n = node0 + nl;
        if (n < N) {
            float w = __expf(lrelu(s2[n] + dds[nl]) - mbs[nl]);
            float4 hv = *(const float4*)&h2[(size_t)n * 16 + 4 * q];  // zero-padded
            accv[qq] = make_float4(w * hv.x, w * hv.y, w * hv.z, w * hv.w);
            den[qq] = w;
        } else { accv[qq] = make_float4(0.f, 0.f, 0.f, 0.f); den[qq] = 0.f; }
    }

    if (total <= CAP) {
        for (int i = tid; i < cnt; i += 512) {
            unsigned p = pairs[jbeg + i];
            int pos = atomicAdd(&lcnt[(p >> 17) & (BNODES - 1)], 1);
            srt[pos] = p & 0x1FFFF;
        }
        __syncthreads();
#pragma unroll
        for (int qq = 0; qq < 2; ++qq) {
            int nl = gg * 2 + qq;
            float dd = dds[nl], mb = mbs[nl];
            int j = lofs[nl], j1 = lofs[nl + 1];
            float4 a = accv[qq]; float dn = den[qq];
            for (; j + 4 <= j1; j += 4) {
                int e0 = srt[j], e1 = srt[j + 1], e2 = srt[j + 2], e3 = srt[j + 3];
                float v0 = s2[e0], v1 = s2[e1], v2 = s2[e2], v3 = s2[e3];
                float4 H0 = *(const float4*)&h2[(size_t)e0 * 16 + 4 * q];
                float4 H1 = *(const float4*)&h2[(size_t)e1 * 16 + 4 * q];
                float4 H2 = *(const float4*)&h2[(size_t)e2 * 16 + 4 * q];
                float4 H3 = *(const float4*)&h2[(size_t)e3 * 16 + 4 * q];
                float w0 = __expf(lrelu(v0 + dd) - mb), w1 = __expf(lrelu(v1 + dd) - mb);
                float w2 = __expf(lrelu(v2 + dd) - mb), w3 = __expf(lrelu(v3 + dd) - mb);
                a.x += w0 * H0.x + w1 * H1.x + w2 * H2.x + w3 * H3.x;
                a.y += w0 * H0.y + w1 * H1.y + w2 * H2.y + w3 * H3.y;
                a.z += w0 * H0.z + w1 * H1.z + w2 * H2.z + w3 * H3.z;
                a.w += w0 * H0.w + w1 * H1.w + w2 * H2.w + w3 * H3.w;
                dn += (w0 + w1) + (w2 + w3);
            }
            for (; j < j1; ++j) {
                int e0 = srt[j];
                float w0 = __expf(lrelu(s2[e0] + dd) - mb);
                float4 H0 = *(const float4*)&h2[(size_t)e0 * 16 + 4 * q];
                a.x += w0 * H0.x; a.y += w0 * H0.y; a.z += w0 * H0.z; a.w += w0 * H0.w;
                dn += w0;
            }
            accv[qq] = a; den[qq] = dn;
        }
        __syncthreads();
    } else {
        for (int i = tid; i < BNODES * 17; i += 512) accs[i] = 0.f;
        __syncthreads();
        for (int i = tid; i < cnt; i += 512) {
            unsigned p = pairs[jbeg + i];
            int src = p & 0x1FFFF, nl = (p >> 17) & (BNODES - 1);
            float w = __expf(lrelu(s2[src] + dds[nl]) - mbs[nl]);
#pragma unroll
            for (int kk = 0; kk < 4; ++kk)
                atomicAdd(&accs[nl * 17 + 4 * q + kk],
                          w * h2[(size_t)src * 16 + 4 * q + kk]);
            if (q == 0) atomicAdd(&accs[nl * 17 + 16], w);
        }
        __syncthreads();
#pragma unroll
        for (int qq = 0; qq < 2; ++qq) {
            int nl = gg * 2 + qq;
            accv[qq].x += accs[nl * 17 + 4 * q + 0];
            accv[qq].y += accs[nl * 17 + 4 * q + 1];
            accv[qq].z += accs[nl * 17 + 4 * q + 2];
            accv[qq].w += accs[nl * 17 + 4 * q + 3];
            den[qq] += accs[nl * 17 + 16];
        }
        __syncthreads();
    }

#pragma unroll
    for (int qq = 0; qq < 2; ++qq) {
        int nl = gg * 2 + qq;
        accs[nl * 17 + 4 * q + 0] = accv[qq].x;
        accs[nl * 17 + 4 * q + 1] = accv[qq].y;
        accs[nl * 17 + 4 * q + 2] = accv[qq].z;
        accs[nl * 17 + 4 * q + 3] = accv[qq].w;
        if (q == 0) accs[nl * 17 + 16] = den[qq];
    }
    __syncthreads();

    int g = tid >> 4, k = tid & 15;
    bool fk = k < 10;
#pragma unroll
    for (int qq = 0; qq < 8; ++qq) {
        int nl = g * 8 + qq, n = node0 + nl;
        if (n >= N) continue;            // group-uniform
        float inv = 1.f / accs[nl * 17 + 16];
        float o = fk ? accs[nl * 17 + k] * inv + sb2g[k] : 0.f;
        float v = sb1[k];
#pragma unroll
        for (int kk = 0; kk < 10; ++kk) {
            float ov = __shfl(o, kk, 16);
            if (fk) v += ov * sW1[kk * 10 + k];
        }
        float t = fmaxf(v, 0.f);
        float cc = t * sW2[k];           // zero for k>=10
#pragma unroll
        for (int off = 1; off < 16; off <<= 1) cc += __shfl_xor(cc, off, 16);
        if (k == 0) out[n] = cc + sbl2;
    }
}

extern "C" void kernel_launch(void* const* d_in, const int* in_sizes, int n_in,
                              void* d_out, int out_size, void* d_ws, size_t ws_size,
                              hipStream_t stream)
{
    const float* x   = (const float*)d_in[0];
    const int*   ei  = (const int*)  d_in[1];   // [2][E] int32
    const float* W1  = (const float*)d_in[2];
    const float* a1s = (const float*)d_in[3];
    const float* a1d = (const float*)d_in[4];
    const float* b1  = (const float*)d_in[5];
    const float* W2  = (const float*)d_in[6];
    const float* a2s = (const float*)d_in[7];
    const float* a2d = (const float*)d_in[8];
    const float* b2  = (const float*)d_in[9];
    const float* Wl1 = (const float*)d_in[10];
    const float* bl1 = (const float*)d_in[11];
    const float* Wl2 = (const float*)d_in[12];
    const float* bl2 = (const float*)d_in[13];

    int N = in_sizes[0] / 128;
    int E = in_sizes[1] / 2;
    const int* ei_src = ei;
    const int* ei_dst = ei + E;
    int NSB = (N + BNODES - 1) >> FSH;       // 391 buckets (<= NSBMAX)

    size_t Np = ((size_t)N + 3) & ~(size_t)3;
    size_t N16 = Np * 16;
    size_t need_bytes = (16 + Np * 36) * 4 + ((size_t)NSB * 18 + 1) * 4 + (size_t)E * 4;
    if (ws_size < need_bytes) return;  // degrade to wrong-answer, never fault

    float*    ws    = (float*)d_ws;
    unsigned* gmax1 = (unsigned*)d_ws;       // [0]
    unsigned* gmax2 = gmax1 + 1;             // [1]
    float* h1 = ws + 16;                     // Np*16
    float* s1 = h1 + N16;                    // Np
    float* d1 = s1 + Np;                     // Np
    float* h2 = d1 + Np;                     // Np*16 (cols 10..15 zero)
    float* s2 = h2 + N16;                    // Np
    float* d2 = s2 + Np;                     // Np
    int* chist  = (int*)(d2 + Np);           // NSB
    int* cboffs = chist + NSB;               // NSB+1
    int* ccur   = cboffs + NSB + 1;          // NSB*16 (1 cursor per 64B)
    unsigned* pairs = (unsigned*)(ccur + (size_t)NSB * 16);  // E

    hipLaunchKernelGGL(k_init, dim3((NSB + 255) / 256), dim3(256), 0, stream, gmax1, chist, NSB);
    hipLaunchKernelGGL(k_gemm1, dim3((N + 63) / 64), dim3(256), 0, stream,
                       x, W1, a1s, a1d, h1, s1, d1, gmax1, N);
    hipLaunchKernelGGL(k_chist, dim3(256), dim3(256), 0, stream, ei_dst, chist, E, NSB);
    hipLaunchKernelGGL(k_cboffs, dim3(1), dim3(64), 0, stream, chist, cboffs, ccur, NSB, E);
    hipLaunchKernelGGL(k_csplit, dim3((E + TILE - 1) / TILE), dim3(512), 0, stream,
                       ei_src, ei_dst, ccur, pairs, E, NSB);
    hipLaunchKernelGGL(k_agg1, dim3(NSB), dim3(512), 0, stream,
                       cboffs, pairs, s1, d1, h1, b1, W2, a2s, a2d, h2, s2, d2,
                       gmax1, gmax2, N);
    hipLaunchKernelGGL(k_agg2, dim3(NSB), dim3(512), 0, stream,
                       cboffs, pairs, s2, d2, h2, b2, Wl1, bl1, Wl2, bl2,
                       gmax2, (float*)d_out, N);
}

// Round 9
// 296.977 us; speedup vs baseline: 3.3982x; 1.1761x over previous
//
#include <hip/hip_runtime.h>
#include <hip/hip_fp16.h>

// GAT (2 layers, heads=1) + 2-layer MLP head. N=100000, E=3200000, D=128.
// R9: R8 structure + (1) h1/h2 stored fp16 -> 32B rows, h fits per-XCD L2,
// (2) parallel bucket-offset scan, (3) register-staged pairs in agg sort.
// Softmax stabilization uses a GLOBAL upper bound m̄_i = leaky(gmax_asrc + adst_i)
// (valid since leaky_relu is monotone); alpha is mathematically unchanged.

#define NEG 0.2f
#define FSH 8
#define BNODES 256           // nodes per bucket
#define NSBMAX 512           // >= ceil(100000/256)=391
#define CAP 9216             // bucket edge capacity (mean 8192, +11 sigma)
#define TILE 8192            // edges per csplit block
#define PES 18               // ceil(CAP/512) register-staged pairs per thread

__device__ __forceinline__ float lrelu(float x) { return x > 0.0f ? x : NEG * x; }

__device__ __forceinline__ unsigned fenc(float f) {
    unsigned u = __float_as_uint(f);
    return (u & 0x80000000u) ? ~u : (u | 0x80000000u);
}
__device__ __forceinline__ float fdec(unsigned e) {
    return (e & 0x80000000u) ? __uint_as_float(e & 0x7FFFFFFFu) : __uint_as_float(~e);
}

// load 4 consecutive halves as float4 (8B load)
__device__ __forceinline__ float4 ldh4(const __half* h, size_t off) {
    uint2 u = *(const uint2*)(h + off);
    __half2 a = *(__half2*)&u.x, b = *(__half2*)&u.y;
    float2 fa = __half22float2(a), fb = __half22float2(b);
    return make_float4(fa.x, fa.y, fb.x, fb.y);
}

__global__ __launch_bounds__(256) void k_init(unsigned* g, int* chist, int NSB) {
    int i = blockIdx.x * 256 + threadIdx.x;
    if (i < NSB) chist[i] = 0;
    if (i < 2) g[i] = 0u;
}

// K1: h1 = x @ W1 (128->16) [fp16 out], s1 = h1·a1s, d1 = h1·a1d, gmax1 = max(s1)
__global__ __launch_bounds__(256) void k_gemm1(
    const float* __restrict__ x, const float* __restrict__ W1,
    const float* __restrict__ a1s, const float* __restrict__ a1d,
    __half* __restrict__ h1, float* __restrict__ s1, float* __restrict__ d1,
    unsigned* __restrict__ gmax, int N)
{
    __shared__ float sW[128 * 16];
    __shared__ float sx[64 * 132];
    __shared__ float wm[4];
    int tid = threadIdx.x;
    for (int i = tid; i < 2048; i += 256) sW[i] = W1[i];
    int node0 = blockIdx.x * 64;
    for (int i = tid; i < 64 * 32; i += 256) {
        int row = i >> 5, c4 = i & 31;
        int n = node0 + row;
        float4 v = make_float4(0.f, 0.f, 0.f, 0.f);
        if (n < N) v = ((const float4*)x)[(size_t)n * 32 + c4];
        *(float4*)&sx[row * 132 + c4 * 4] = v;
    }
    __syncthreads();

    int node = node0 + (tid >> 2);
    int grp  = tid & 3;
    const float* xr = &sx[(tid >> 2) * 132];
    float4 acc = make_float4(0.f, 0.f, 0.f, 0.f);
#pragma unroll 8
    for (int j = 0; j < 128; ++j) {
        float xv = xr[j];
        float4 w = *(const float4*)&sW[j * 16 + grp * 4];
        acc.x += xv * w.x; acc.y += xv * w.y; acc.z += xv * w.z; acc.w += xv * w.w;
    }
    float4 as = ((const float4*)a1s)[grp];
    float4 ad = ((const float4*)a1d)[grp];
    float sv = acc.x * as.x + acc.y * as.y + acc.z * as.z + acc.w * as.w;
    float dv = acc.x * ad.x + acc.y * ad.y + acc.z * ad.z + acc.w * ad.w;
    sv += __shfl_xor(sv, 1); sv += __shfl_xor(sv, 2);
    dv += __shfl_xor(dv, 1); dv += __shfl_xor(dv, 2);
    if (node < N) {
        __half2 p0 = __floats2half2_rn(acc.x, acc.y);
        __half2 p1 = __floats2half2_rn(acc.z, acc.w);
        uint2 u; u.x = *(unsigned*)&p0; u.y = *(unsigned*)&p1;
        *(uint2*)&h1[(size_t)node * 16 + grp * 4] = u;
        if (grp == 0) { s1[node] = sv; d1[node] = dv; }
    }
    float m = (node < N) ? sv : -3.4e38f;
#pragma unroll
    for (int off = 32; off >= 1; off >>= 1) m = fmaxf(m, __shfl_xor(m, off));
    if ((tid & 63) == 0) wm[tid >> 6] = m;
    __syncthreads();
    if (tid == 0) {
        float b = fmaxf(fmaxf(wm[0], wm[1]), fmaxf(wm[2], wm[3]));
        atomicMax(gmax, fenc(b));
    }
}

// bucket histogram (dst>>8), LDS-aggregated
__global__ __launch_bounds__(256) void k_chist(const int* __restrict__ edst,
                                               int* __restrict__ chist, int E, int NSB) {
    __shared__ int lc[NSBMAX];
    int tid = threadIdx.x;
    for (int i = tid; i < NSB; i += 256) lc[i] = 0;
    __syncthreads();
    int stride = gridDim.x * 256;
    for (int e = blockIdx.x * 256 + tid; e < E; e += stride)
        atomicAdd(&lc[edst[e] >> FSH], 1);
    __syncthreads();
    for (int i = tid; i < NSB; i += 256) { int v = lc[i]; if (v) atomicAdd(&chist[i], v); }
}

// parallel exclusive scan of bucket counts -> cboffs[NSB+1]; init padded cursors
__global__ __launch_bounds__(512) void k_cboffs(const int* __restrict__ chist,
                                                int* __restrict__ cboffs, int* __restrict__ ccur,
                                                int NSB, int E) {
    __shared__ int wsum[8];
    int tid = threadIdx.x;
    int c = (tid < NSB) ? chist[tid] : 0;
    int pfx = c;
#pragma unroll
    for (int off = 1; off < 64; off <<= 1) {
        int t = __shfl_up(pfx, off, 64);
        if ((tid & 63) >= off) pfx += t;
    }
    if ((tid & 63) == 63) wsum[tid >> 6] = pfx;
    __syncthreads();
    int carry = 0;
    for (int w = 0; w < (tid >> 6); ++w) carry += wsum[w];
    pfx += carry;
    if (tid < NSB) { cboffs[tid] = pfx - c; ccur[tid * 16] = pfx - c; }
    if (tid == 0) cboffs[NSB] = E;
}

// split: LDS-sort a tile of 8192 edges by 256-node bucket, flush run-granular
__global__ __launch_bounds__(512) void k_csplit(
    const int* __restrict__ esrc, const int* __restrict__ edst,
    int* __restrict__ ccur, unsigned* __restrict__ pairs, int E, int NSB)
{
    __shared__ unsigned lsrt[TILE];
    __shared__ int lhist[NSBMAX];        // counts -> cursors
    __shared__ int lofs[NSBMAX + 1];
    __shared__ int gbase[NSBMAX];
    __shared__ int wsum[8];
    int tid = threadIdx.x;
    int base = blockIdx.x * TILE;
    int tcnt = min(TILE, E - base);
    for (int i = tid; i < NSB; i += 512) lhist[i] = 0;
    __syncthreads();
    for (int i = tid; i < tcnt; i += 512)
        atomicAdd(&lhist[edst[base + i] >> FSH], 1);
    __syncthreads();
    int c = (tid < NSB) ? lhist[tid] : 0;
    int pfx = c;
#pragma unroll
    for (int off = 1; off < 64; off <<= 1) {
        int t = __shfl_up(pfx, off, 64);
        if ((tid & 63) >= off) pfx += t;
    }
    if ((tid & 63) == 63) wsum[tid >> 6] = pfx;
    __syncthreads();
    int carry = 0;
    for (int w = 0; w < (tid >> 6); ++w) carry += wsum[w];
    pfx += carry;
    if (tid < NSB) {
        lofs[tid + 1] = pfx;
        gbase[tid] = c ? atomicAdd(&ccur[tid * 16], c) : 0;
        lhist[tid] = pfx - c;            // cursor
    }
    if (tid == 0) lofs[0] = 0;
    __syncthreads();
    for (int i = tid; i < tcnt; i += 512) {
        int e = base + i;
        int d = edst[e], s = esrc[e];
        int pos = atomicAdd(&lhist[d >> FSH], 1);
        lsrt[pos] = ((unsigned)(d & (BNODES - 1)) << 17) | (unsigned)s;
    }
    __syncthreads();
    for (int i = tid; i < tcnt; i += 512) {
        int lo = 0, hi = NSB - 1;
        while (lo < hi) { int mid = (lo + hi + 1) >> 1; if (lofs[mid] <= i) lo = mid; else hi = mid - 1; }
        pairs[gbase[lo] + (i - lofs[lo])] = lsrt[i];
    }
}

// ---- layer-1 agg: own-bucket LDS sort (reg-staged) + 4-lane fp16 gather ----
__global__ __launch_bounds__(512) void k_agg1(
    const int* __restrict__ boffs, const unsigned* __restrict__ pairs,
    const float* __restrict__ s1, const float* __restrict__ d1, const __half* __restrict__ h1,
    const float* __restrict__ b1, const float* __restrict__ W2,
    const float* __restrict__ a2s, const float* __restrict__ a2d,
    __half* __restrict__ h2, float* __restrict__ s2, float* __restrict__ d2,
    const unsigned* __restrict__ gmax1p, unsigned* __restrict__ gmax2, int N)
{
    __shared__ unsigned srt[CAP];
    __shared__ float accs[BNODES * 17];
    __shared__ int lcnt[BNODES];
    __shared__ int lofs[BNODES + 1];
    __shared__ float dds[BNODES], mbs[BNODES];
    __shared__ float sW[160], sb[16], sas[16], sad[16];
    __shared__ int wsum[8];
    __shared__ float wm[8];

    int tid = threadIdx.x;
    int fb = blockIdx.x;
    if (tid < 160) sW[tid] = W2[tid];
    if (tid < 16) {
        sb[tid]  = b1[tid];
        sas[tid] = (tid < 10) ? a2s[tid] : 0.f;
        sad[tid] = (tid < 10) ? a2d[tid] : 0.f;
    }
    int node0 = fb << FSH;
    float g0 = fdec(*gmax1p);
    if (tid < BNODES) {
        int n = node0 + tid;
        float dd = (n < N) ? d1[n] : 0.f;
        dds[tid] = dd; mbs[tid] = lrelu(g0 + dd);
        lcnt[tid] = 0;
    }
    __syncthreads();

    int jbeg = boffs[fb], jend = boffs[fb + 1];
    int cnt = jend - jbeg;

    // count pass with register staging (single global read of pairs)
    unsigned pe[PES];
#pragma unroll
    for (int u = 0; u < PES; ++u) {
        int i = tid + u * 512;
        bool ok = (i < cnt);
        pe[u] = ok ? pairs[jbeg + i] : 0u;
        if (ok) atomicAdd(&lcnt[(pe[u] >> 17) & (BNODES - 1)], 1);
    }
    __syncthreads();
    // 256-key scan (padded to 512 threads)
    int c = (tid < BNODES) ? lcnt[tid] : 0;
    int pfx = c;
#pragma unroll
    for (int off = 1; off < 64; off <<= 1) {
        int t = __shfl_up(pfx, off, 64);
        if ((tid & 63) >= off) pfx += t;
    }
    if ((tid & 63) == 63) wsum[tid >> 6] = pfx;
    __syncthreads();
    int carry = 0;
    for (int w = 0; w < (tid >> 6); ++w) carry += wsum[w];
    pfx += carry;
    if (tid < BNODES) { lofs[tid + 1] = pfx; lcnt[tid] = pfx - c; }
    if (tid == 0) lofs[0] = 0;
    __syncthreads();
    int total = lofs[BNODES];

    int gg = tid >> 2, q = tid & 3;      // 128 gather groups x 4 lanes
    float4 accv[2]; float den[2];
#pragma unroll
    for (int qq = 0; qq < 2; ++qq) {
        int nl = gg * 2 + qq, n = node0 + nl;
        if (n < N) {
            float w = __expf(lrelu(s1[n] + dds[nl]) - mbs[nl]);
            float4 hv = ldh4(h1, (size_t)n * 16 + 4 * q);
            accv[qq] = make_float4(w * hv.x, w * hv.y, w * hv.z, w * hv.w);
            den[qq] = w;
        } else { accv[qq] = make_float4(0.f, 0.f, 0.f, 0.f); den[qq] = 0.f; }
    }

    if (total <= CAP && cnt <= CAP) {
        // scatter pass from registers -> dst-sorted srcs
#pragma unroll
        for (int u = 0; u < PES; ++u) {
            int i = tid + u * 512;
            if (i < cnt) {
                unsigned p = pe[u];
                int pos = atomicAdd(&lcnt[(p >> 17) & (BNODES - 1)], 1);
                srt[pos] = p & 0x1FFFF;
            }
        }
        __syncthreads();
        // register gather: 4-way unrolled chains, 32B fp16 h-rows
#pragma unroll
        for (int qq = 0; qq < 2; ++qq) {
            int nl = gg * 2 + qq;
            float dd = dds[nl], mb = mbs[nl];
            int j = lofs[nl], j1 = lofs[nl + 1];
            float4 a = accv[qq]; float dn = den[qq];
            for (; j + 4 <= j1; j += 4) {
                int e0 = srt[j], e1 = srt[j + 1], e2 = srt[j + 2], e3 = srt[j + 3];
                float v0 = s1[e0], v1 = s1[e1], v2 = s1[e2], v3 = s1[e3];
                float4 H0 = ldh4(h1, (size_t)e0 * 16 + 4 * q);
                float4 H1 = ldh4(h1, (size_t)e1 * 16 + 4 * q);
                float4 H2 = ldh4(h1, (size_t)e2 * 16 + 4 * q);
                float4 H3 = ldh4(h1, (size_t)e3 * 16 + 4 * q);
                float w0 = __expf(lrelu(v0 + dd) - mb), w1 = __expf(lrelu(v1 + dd) - mb);
                float w2 = __expf(lrelu(v2 + dd) - mb), w3 = __expf(lrelu(v3 + dd) - mb);
                a.x += w0 * H0.x + w1 * H1.x + w2 * H2.x + w3 * H3.x;
                a.y += w0 * H0.y + w1 * H1.y + w2 * H2.y + w3 * H3.y;
                a.z += w0 * H0.z + w1 * H1.z + w2 * H2.z + w3 * H3.z;
                a.w += w0 * H0.w + w1 * H1.w + w2 * H2.w + w3 * H3.w;
                dn += (w0 + w1) + (w2 + w3);
            }
            for (; j < j1; ++j) {
                int e0 = srt[j];
                float w0 = __expf(lrelu(s1[e0] + dd) - mb);
                float4 H0 = ldh4(h1, (size_t)e0 * 16 + 4 * q);
                a.x += w0 * H0.x; a.y += w0 * H0.y; a.z += w0 * H0.z; a.w += w0 * H0.w;
                dn += w0;
            }
            accv[qq] = a; den[qq] = dn;
        }
        __syncthreads();
    } else {
        // fallback (statistically unreachable)
        for (int i = tid; i < BNODES * 17; i += 512) accs[i] = 0.f;
        __syncthreads();
        for (int i = tid; i < cnt; i += 512) {
            unsigned p = pairs[jbeg + i];
            int src = p & 0x1FFFF, nl = (p >> 17) & (BNODES - 1);
            float w = __expf(lrelu(s1[src] + dds[nl]) - mbs[nl]);
            float4 H = ldh4(h1, (size_t)src * 16 + 4 * q);
            atomicAdd(&accs[nl * 17 + 4 * q + 0], w * H.x);
            atomicAdd(&accs[nl * 17 + 4 * q + 1], w * H.y);
            atomicAdd(&accs[nl * 17 + 4 * q + 2], w * H.z);
            atomicAdd(&accs[nl * 17 + 4 * q + 3], w * H.w);
            if (q == 0) atomicAdd(&accs[nl * 17 + 16], w);
        }
        __syncthreads();
#pragma unroll
        for (int qq = 0; qq < 2; ++qq) {
            int nl = gg * 2 + qq;
            accv[qq].x += accs[nl * 17 + 4 * q + 0];
            accv[qq].y += accs[nl * 17 + 4 * q + 1];
            accv[qq].z += accs[nl * 17 + 4 * q + 2];
            accv[qq].w += accs[nl * 17 + 4 * q + 3];
            den[qq] += accs[nl * 17 + 16];
        }
        __syncthreads();
    }

    // stage accumulators to LDS (stride-17 rows)
#pragma unroll
    for (int qq = 0; qq < 2; ++qq) {
        int nl = gg * 2 + qq;
        accs[nl * 17 + 4 * q + 0] = accv[qq].x;
        accs[nl * 17 + 4 * q + 1] = accv[qq].y;
        accs[nl * 17 + 4 * q + 2] = accv[qq].z;
        accs[nl * 17 + 4 * q + 3] = accv[qq].w;
        if (q == 0) accs[nl * 17 + 16] = den[qq];
    }
    __syncthreads();

    // epilogue: 32 groups of 16 lanes, 8 nodes each
    int g = tid >> 4, k = tid & 15;
    float sval = -3.4e38f;
#pragma unroll
    for (int qq = 0; qq < 8; ++qq) {
        int nl = g * 8 + qq, n = node0 + nl;
        if (n >= N) continue;            // group-uniform
        float inv = 1.f / accs[nl * 17 + 16];
        float o = fmaxf(accs[nl * 17 + k] * inv + sb[k], 0.f);
        float hh = 0.f;
#pragma unroll
        for (int kk = 0; kk < 16; ++kk) {
            float ov = __shfl(o, kk, 16);
            if (k < 10) hh += ov * sW[kk * 10 + k];
        }
        if (k >= 10) hh = 0.f;
        float ts = hh * sas[k];
        float td = hh * sad[k];
#pragma unroll
        for (int off = 1; off < 16; off <<= 1) {
            ts += __shfl_xor(ts, off, 16);
            td += __shfl_xor(td, off, 16);
        }
        h2[(size_t)n * 16 + k] = __float2half_rn(hh);   // zero-padded cols 10..15
        if (k == 0) { s2[n] = ts; d2[n] = td; }
        sval = fmaxf(sval, ts);
    }
    float m = sval;
#pragma unroll
    for (int off = 32; off >= 1; off >>= 1) m = fmaxf(m, __shfl_xor(m, off));
    if ((tid & 63) == 0) wm[tid >> 6] = m;
    __syncthreads();
    if (tid == 0) {
        float b = wm[0];
#pragma unroll
        for (int i = 1; i < 8; ++i) b = fmaxf(b, wm[i]);
        atomicMax(gmax2, fenc(b));
    }
}

// ---- layer-2 agg (same structure) + norm/bias + MLP head -> out ----
__global__ __launch_bounds__(512) void k_agg2(
    const int* __restrict__ boffs, const unsigned* __restrict__ pairs,
    const float* __restrict__ s2, const float* __restrict__ d2, const __half* __restrict__ h2,
    const float* __restrict__ b2, const float* __restrict__ Wl1, const float* __restrict__ bl1,
    const float* __restrict__ Wl2, const float* __restrict__ bl2,
    const unsigned* __restrict__ gmax2p, float* __restrict__ out, int N)
{
    __shared__ unsigned srt[CAP];
    __shared__ float accs[BNODES * 17];
    __shared__ int lcnt[BNODES];
    __shared__ int lofs[BNODES + 1];
    __shared__ float dds[BNODES], mbs[BNODES];
    __shared__ float sW1[100], sb1[16], sW2[16], sb2g[16];
    __shared__ float sbl2;
    __shared__ int wsum[8];

    int tid = threadIdx.x;
    int fb = blockIdx.x;
    if (tid < 100) sW1[tid] = Wl1[tid];
    if (tid < 16) {
        sb1[tid]  = (tid < 10) ? bl1[tid] : 0.f;
        sW2[tid]  = (tid < 10) ? Wl2[tid] : 0.f;
        sb2g[tid] = (tid < 10) ? b2[tid]  : 0.f;
    }
    if (tid == 0) sbl2 = bl2[0];
    int node0 = fb << FSH;
    float g0 = fdec(*gmax2p);
    if (tid < BNODES) {
        int n = node0 + tid;
        float dd = (n < N) ? d2[n] : 0.f;
        dds[tid] = dd; mbs[tid] = lrelu(g0 + dd);
        lcnt[tid] = 0;
    }
    __syncthreads();

    int jbeg = boffs[fb], jend = boffs[fb + 1];
    int cnt = jend - jbeg;

    unsigned pe[PES];
#pragma unroll
    for (int u = 0; u < PES; ++u) {
        int i = tid + u * 512;
        bool ok = (i < cnt);
        pe[u] = ok ? pairs[jbeg + i] : 0u;
        if (ok) atomicAdd(&lcnt[(pe[u] >> 17) & (BNODES - 1)], 1);
    }
    __syncthreads();
    int c = (tid < BNODES) ? lcnt[tid] : 0;
    int pfx = c;
#pragma unroll
    for (int off = 1; off < 64; off <<= 1) {
        int t = __shfl_up(pfx, off, 64);
        if ((tid & 63) >= off) pfx += t;
    }
    if ((tid & 63) == 63) wsum[tid >> 6] = pfx;
    __syncthreads();
    int carry = 0;
    for (int w = 0; w < (tid >> 6); ++w) carry += wsum[w];
    pfx += carry;
    if (tid < BNODES) { lofs[tid + 1] = pfx; lcnt[tid] = pfx - c; }
    if (tid == 0) lofs[0] = 0;
    __syncthreads();
    int total = lofs[BNODES];

    int gg = tid >> 2, q = tid & 3;
    float4 accv[2]; float den[2];
#pragma unroll
    for (int qq = 0; qq < 2; ++qq) {
        int nl = gg * 2 + qq, n = node0 + nl;
        if (n < N) {
            float w = __expf(lrelu(s2[n] + dds[nl]) - mbs[nl]);
            float4 hv = ldh4(h2, (size_t)n * 16 + 4 * q);   // zero-padded
            accv[qq] = make_float4(w * hv.x, w * hv.y, w * hv.z, w * hv.w);
            den[qq] = w;
        } else { accv[qq] = make_float4(0.f, 0.f, 0.f, 0.f); den[qq] = 0.f; }
    }

    if (total <= CAP && cnt <= CAP) {
#pragma unroll
        for (int u = 0; u < PES; ++u) {
            int i = tid + u * 512;
            if (i < cnt) {
                unsigned p = pe[u];
                int pos = atomicAdd(&lcnt[(p >> 17) & (BNODES - 1)], 1);
                srt[pos] = p & 0x1FFFF;
            }
        }
        __syncthreads();
#pragma unroll
        for (int qq = 0; qq < 2; ++qq) {
            int nl = gg * 2 + qq;
            float dd = dds[nl], mb = mbs[nl];
            int j = lofs[nl], j1 = lofs[nl + 1];
            float4 a = accv[qq]; float dn = den[qq];
            for (; j + 4 <= j1; j += 4) {
                int e0 = srt[j], e1 = srt[j + 1], e2 = srt[j + 2], e3 = srt[j + 3];
                float v0 = s2[e0], v1 = s2[e1], v2 = s2[e2], v3 = s2[e3];
                float4 H0 = ldh4(h2, (size_t)e0 * 16 + 4 * q);
                float4 H1 = ldh4(h2, (size_t)e1 * 16 + 4 * q);
                float4 H2 = ldh4(h2, (size_t)e2 * 16 + 4 * q);
                float4 H3 = ldh4(h2, (size_t)e3 * 16 + 4 * q);
                float w0 = __expf(lrelu(v0 + dd) - mb), w1 = __expf(lrelu(v1 + dd) - mb);
                float w2 = __expf(lrelu(v2 + dd) - mb), w3 = __expf(lrelu(v3 + dd) - mb);
                a.x += w0 * H0.x + w1 * H1.x + w2 * H2.x + w3 * H3.x;
                a.y += w0 * H0.y + w1 * H1.y + w2 * H2.y + w3 * H3.y;
                a.z += w0 * H0.z + w1 * H1.z + w2 * H2.z + w3 * H3.z;
                a.w += w0 * H0.w + w1 * H1.w + w2 * H2.w + w3 * H3.w;
                dn += (w0 + w1) + (w2 + w3);
            }
            for (; j < j1; ++j) {
                int e0 = srt[j];
                float w0 = __expf(lrelu(s2[e0] + dd) - mb);
                float4 H0 = ldh4(h2, (size_t)e0 * 16 + 4 * q);
                a.x += w0 * H0.x; a.y += w0 * H0.y; a.z += w0 * H0.z; a.w += w0 * H0.w;
                dn += w0;
            }
            accv[qq] = a; den[qq] = dn;
        }
        __syncthreads();
    } else {
        for (int i = tid; i < BNODES * 17; i += 512) accs[i] = 0.f;
        __syncthreads();
        for (int i = tid; i < cnt; i += 512) {
            unsigned p = pairs[jbeg + i];
            int src = p & 0x1FFFF, nl = (p >> 17) & (BNODES - 1);
            float w = __expf(lrelu(s2[src] + dds[nl]) - mbs[nl]);
            float4 H = ldh4(h2, (size_t)src * 16 + 4 * q);
            atomicAdd(&accs[nl * 17 + 4 * q + 0], w * H.x);
            atomicAdd(&accs[nl * 17 + 4 * q + 1], w * H.y);
            atomicAdd(&accs[nl * 17 + 4 * q + 2], w * H.z);
            atomicAdd(&accs[nl * 17 + 4 * q + 3], w * H.w);
            if (q == 0) atomicAdd(&accs[nl * 17 + 16], w);
        }
        __syncthreads();
#pragma unroll
        for (int qq = 0; qq < 2; ++qq) {
            int nl = gg * 2 + qq;
            accv[qq].x += accs[nl * 17 + 4 * q + 0];
            accv[qq].y += accs[nl * 17 + 4 * q + 1];
            accv[qq].z += accs[nl * 17 + 4 * q + 2];
            accv[qq].w += accs[nl * 17 + 4 * q + 3];
            den[qq] += accs[nl * 17 + 16];
        }
        __syncthreads();
    }

#pragma unroll
    for (int qq = 0; qq < 2; ++qq) {
        int nl = gg * 2 + qq;
        accs[nl * 17 + 4 * q + 0] = accv[qq].x;
        accs[nl * 17 + 4 * q + 1] = accv[qq].y;
        accs[nl * 17 + 4 * q + 2] = accv[qq].z;
        accs[nl * 17 + 4 * q + 3] = accv[qq].w;
        if (q == 0) accs[nl * 17 + 16] = den[qq];
    }
    __syncthreads();

    int g = tid >> 4, k = tid & 15;
    bool fk = k < 10;
#pragma unroll
    for (int qq = 0; qq < 8; ++qq) {
        int nl = g * 8 + qq, n = node0 + nl;
        if (n >= N) continue;            // group-uniform
        float inv = 1.f / accs[nl * 17 + 16];
        float o = fk ? accs[nl * 17 + k] * inv + sb2g[k] : 0.f;
        float v = sb1[k];
#pragma unroll
        for (int kk = 0; kk < 10; ++kk) {
            float ov = __shfl(o, kk, 16);
            if (fk) v += ov * sW1[kk * 10 + k];
        }
        float t = fmaxf(v, 0.f);
        float cc = t * sW2[k];           // zero for k>=10
#pragma unroll
        for (int off = 1; off < 16; off <<= 1) cc += __shfl_xor(cc, off, 16);
        if (k == 0) out[n] = cc + sbl2;
    }
}

extern "C" void kernel_launch(void* const* d_in, const int* in_sizes, int n_in,
                              void* d_out, int out_size, void* d_ws, size_t ws_size,
                              hipStream_t stream)
{
    const float* x   = (const float*)d_in[0];
    const int*   ei  = (const int*)  d_in[1];   // [2][E] int32
    const float* W1  = (const float*)d_in[2];
    const float* a1s = (const float*)d_in[3];
    const float* a1d = (const float*)d_in[4];
    const float* b1  = (const float*)d_in[5];
    const float* W2  = (const float*)d_in[6];
    const float* a2s = (const float*)d_in[7];
    const float* a2d = (const float*)d_in[8];
    const float* b2  = (const float*)d_in[9];
    const float* Wl1 = (const float*)d_in[10];
    const float* bl1 = (const float*)d_in[11];
    const float* Wl2 = (const float*)d_in[12];
    const float* bl2 = (const float*)d_in[13];

    int N = in_sizes[0] / 128;
    int E = in_sizes[1] / 2;
    const int* ei_src = ei;
    const int* ei_dst = ei + E;
    int NSB = (N + BNODES - 1) >> FSH;       // 391 buckets (<= NSBMAX)

    size_t Np = ((size_t)N + 3) & ~(size_t)3;
    // floats: 16 hdr + h1(8*Np as half=16) + s1 + d1 + h2(8) + s2 + d2 = 16 + 20*Np
    size_t need_bytes = (16 + Np * 20) * 4 + ((size_t)NSB * 18 + 1) * 4 + (size_t)E * 4;
    if (ws_size < need_bytes) return;  // degrade to wrong-answer, never fault

    float*    ws    = (float*)d_ws;
    unsigned* gmax1 = (unsigned*)d_ws;       // [0]
    unsigned* gmax2 = gmax1 + 1;             // [1]
    __half* h1 = (__half*)(ws + 16);         // Np*16 halves (= Np*8 floats)
    float* s1 = ws + 16 + Np * 8;            // Np
    float* d1 = s1 + Np;                     // Np
    __half* h2 = (__half*)(d1 + Np);         // Np*16 halves (cols 10..15 zero)
    float* s2 = (float*)(h2) + Np * 8;       // Np
    float* d2 = s2 + Np;                     // Np
    int* chist  = (int*)(d2 + Np);           // NSB
    int* cboffs = chist + NSB;               // NSB+1
    int* ccur   = cboffs + NSB + 1;          // NSB*16 (1 cursor per 64B)
    unsigned* pairs = (unsigned*)(ccur + (size_t)NSB * 16);  // E

    hipLaunchKernelGGL(k_init, dim3((NSB + 255) / 256), dim3(256), 0, stream, gmax1, chist, NSB);
    hipLaunchKernelGGL(k_gemm1, dim3((N + 63) / 64), dim3(256), 0, stream,
                       x, W1, a1s, a1d, h1, s1, d1, gmax1, N);
    hipLaunchKernelGGL(k_chist, dim3(256), dim3(256), 0, stream, ei_dst, chist, E, NSB);
    hipLaunchKernelGGL(k_cboffs, dim3(1), dim3(512), 0, stream, chist, cboffs, ccur, NSB, E);
    hipLaunchKernelGGL(k_csplit, dim3((E + TILE - 1) / TILE), dim3(512), 0, stream,
                       ei_src, ei_dst, ccur, pairs, E, NSB);
    hipLaunchKernelGGL(k_agg1, dim3(NSB), dim3(512), 0, stream,
                       cboffs, pairs, s1, d1, h1, b1, W2, a2s, a2d, h2, s2, d2,
                       gmax1, gmax2, N);
    hipLaunchKernelGGL(k_agg2, dim3(NSB), dim3(512), 0, stream,
                       cboffs, pairs, s2, d2, h2, b2, Wl1, bl1, Wl2, bl2,
                       gmax2, (float*)d_out, N);
}

// Round 10
// 292.738 us; speedup vs baseline: 3.4474x; 1.0145x over previous
//
#include <hip/hip_runtime.h>
#include <hip/hip_fp16.h>

// GAT (2 layers, heads=1) + 2-layer MLP head. N=100000, E=3200000, D=128.
// R10: 128-node buckets (782 blocks, ~30KB LDS -> 3-4 blocks/CU), shared-exp
// gather (1 exp/edge via width-4 shfl), fp16 h rows (L2-resident), one-shot
// bucket split with run-granular flushes.
// Softmax stabilization uses a GLOBAL upper bound m̄_i = leaky(gmax_asrc + adst_i)
// (valid since leaky_relu is monotone); alpha is mathematically unchanged.

#define NEG 0.2f
#define FSH 7
#define BNODES 128           // nodes per bucket
#define NSBMAX 1024          // >= ceil(100000/128)=782
#define CAP 4608             // bucket edge capacity (mean 4096, +8 sigma)
#define TILE 8192            // edges per csplit block
#define PES 9                // ceil(CAP/512) register-staged pairs per thread

__device__ __forceinline__ float lrelu(float x) { return x > 0.0f ? x : NEG * x; }

__device__ __forceinline__ unsigned fenc(float f) {
    unsigned u = __float_as_uint(f);
    return (u & 0x80000000u) ? ~u : (u | 0x80000000u);
}
__device__ __forceinline__ float fdec(unsigned e) {
    return (e & 0x80000000u) ? __uint_as_float(e & 0x7FFFFFFFu) : __uint_as_float(~e);
}

// load 4 consecutive halves as float4 (8B load)
__device__ __forceinline__ float4 ldh4(const __half* h, size_t off) {
    uint2 u = *(const uint2*)(h + off);
    __half2 a = *(__half2*)&u.x, b = *(__half2*)&u.y;
    float2 fa = __half22float2(a), fb = __half22float2(b);
    return make_float4(fa.x, fa.y, fb.x, fb.y);
}

__global__ __launch_bounds__(256) void k_init(unsigned* g, int* chist, int NSB) {
    int i = blockIdx.x * 256 + threadIdx.x;
    if (i < NSB) chist[i] = 0;
    if (i < 2) g[i] = 0u;
}

// K1: h1 = x @ W1 (128->16) [fp16 out], s1 = h1·a1s, d1 = h1·a1d, gmax1 = max(s1)
__global__ __launch_bounds__(256) void k_gemm1(
    const float* __restrict__ x, const float* __restrict__ W1,
    const float* __restrict__ a1s, const float* __restrict__ a1d,
    __half* __restrict__ h1, float* __restrict__ s1, float* __restrict__ d1,
    unsigned* __restrict__ gmax, int N)
{
    __shared__ float sW[128 * 16];
    __shared__ float sx[64 * 132];
    __shared__ float wm[4];
    int tid = threadIdx.x;
    for (int i = tid; i < 2048; i += 256) sW[i] = W1[i];
    int node0 = blockIdx.x * 64;
    for (int i = tid; i < 64 * 32; i += 256) {
        int row = i >> 5, c4 = i & 31;
        int n = node0 + row;
        float4 v = make_float4(0.f, 0.f, 0.f, 0.f);
        if (n < N) v = ((const float4*)x)[(size_t)n * 32 + c4];
        *(float4*)&sx[row * 132 + c4 * 4] = v;
    }
    __syncthreads();

    int node = node0 + (tid >> 2);
    int grp  = tid & 3;
    const float* xr = &sx[(tid >> 2) * 132];
    float4 acc = make_float4(0.f, 0.f, 0.f, 0.f);
#pragma unroll 8
    for (int j = 0; j < 128; ++j) {
        float xv = xr[j];
        float4 w = *(const float4*)&sW[j * 16 + grp * 4];
        acc.x += xv * w.x; acc.y += xv * w.y; acc.z += xv * w.z; acc.w += xv * w.w;
    }
    float4 as = ((const float4*)a1s)[grp];
    float4 ad = ((const float4*)a1d)[grp];
    float sv = acc.x * as.x + acc.y * as.y + acc.z * as.z + acc.w * as.w;
    float dv = acc.x * ad.x + acc.y * ad.y + acc.z * ad.z + acc.w * ad.w;
    sv += __shfl_xor(sv, 1); sv += __shfl_xor(sv, 2);
    dv += __shfl_xor(dv, 1); dv += __shfl_xor(dv, 2);
    if (node < N) {
        __half2 p0 = __floats2half2_rn(acc.x, acc.y);
        __half2 p1 = __floats2half2_rn(acc.z, acc.w);
        uint2 u; u.x = *(unsigned*)&p0; u.y = *(unsigned*)&p1;
        *(uint2*)&h1[(size_t)node * 16 + grp * 4] = u;
        if (grp == 0) { s1[node] = sv; d1[node] = dv; }
    }
    float m = (node < N) ? sv : -3.4e38f;
#pragma unroll
    for (int off = 32; off >= 1; off >>= 1) m = fmaxf(m, __shfl_xor(m, off));
    if ((tid & 63) == 0) wm[tid >> 6] = m;
    __syncthreads();
    if (tid == 0) {
        float b = fmaxf(fmaxf(wm[0], wm[1]), fmaxf(wm[2], wm[3]));
        atomicMax(gmax, fenc(b));
    }
}

// bucket histogram (dst>>7), LDS-aggregated
__global__ __launch_bounds__(256) void k_chist(const int* __restrict__ edst,
                                               int* __restrict__ chist, int E, int NSB) {
    __shared__ int lc[NSBMAX];
    int tid = threadIdx.x;
    for (int i = tid; i < NSB; i += 256) lc[i] = 0;
    __syncthreads();
    int stride = gridDim.x * 256;
    for (int e = blockIdx.x * 256 + tid; e < E; e += stride)
        atomicAdd(&lc[edst[e] >> FSH], 1);
    __syncthreads();
    for (int i = tid; i < NSB; i += 256) { int v = lc[i]; if (v) atomicAdd(&chist[i], v); }
}

// parallel exclusive scan (2 entries/thread) -> cboffs[NSB+1]; init padded cursors
__global__ __launch_bounds__(512) void k_cboffs(const int* __restrict__ chist,
                                                int* __restrict__ cboffs, int* __restrict__ ccur,
                                                int NSB, int E) {
    __shared__ int wsum[8];
    int tid = threadIdx.x;
    int i0 = 2 * tid, i1 = i0 + 1;
    int a = (i0 < NSB) ? chist[i0] : 0;
    int b = (i1 < NSB) ? chist[i1] : 0;
    int s = a + b, pfx = s;
#pragma unroll
    for (int off = 1; off < 64; off <<= 1) {
        int t = __shfl_up(pfx, off, 64);
        if ((tid & 63) >= off) pfx += t;
    }
    if ((tid & 63) == 63) wsum[tid >> 6] = pfx;
    __syncthreads();
    int carry = 0;
    for (int w = 0; w < (tid >> 6); ++w) carry += wsum[w];
    int excl = pfx + carry - s;
    if (i0 < NSB) { cboffs[i0] = excl;     ccur[i0 * 16] = excl; }
    if (i1 < NSB) { cboffs[i1] = excl + a; ccur[i1 * 16] = excl + a; }
    if (tid == 0) cboffs[NSB] = E;
}

// split: LDS-sort a tile of 8192 edges by 128-node bucket, flush run-granular
__global__ __launch_bounds__(512) void k_csplit(
    const int* __restrict__ esrc, const int* __restrict__ edst,
    int* __restrict__ ccur, unsigned* __restrict__ pairs, int E, int NSB)
{
    __shared__ unsigned lsrt[TILE];
    __shared__ int lhist[NSBMAX];        // counts -> cursors
    __shared__ int lofs[NSBMAX];         // exclusive run starts (lofs[NSB] unused)
    __shared__ int gbase[NSBMAX];
    __shared__ int wsum[8];
    int tid = threadIdx.x;
    int base = blockIdx.x * TILE;
    int tcnt = min(TILE, E - base);
    for (int i = tid; i < NSB; i += 512) lhist[i] = 0;
    __syncthreads();
    for (int i = tid; i < tcnt; i += 512)
        atomicAdd(&lhist[edst[base + i] >> FSH], 1);
    __syncthreads();
    int i0 = 2 * tid, i1 = i0 + 1;
    int a = (i0 < NSB) ? lhist[i0] : 0;
    int b = (i1 < NSB) ? lhist[i1] : 0;
    int s = a + b, pfx = s;
#pragma unroll
    for (int off = 1; off < 64; off <<= 1) {
        int t = __shfl_up(pfx, off, 64);
        if ((tid & 63) >= off) pfx += t;
    }
    if ((tid & 63) == 63) wsum[tid >> 6] = pfx;
    __syncthreads();
    int carry = 0;
    for (int w = 0; w < (tid >> 6); ++w) carry += wsum[w];
    int excl = pfx + carry - s;
    if (i0 < NSB) {
        lofs[i0] = excl;
        gbase[i0] = a ? atomicAdd(&ccur[i0 * 16], a) : 0;
    }
    if (i1 < NSB) {
        lofs[i1] = excl + a;
        gbase[i1] = b ? atomicAdd(&ccur[i1 * 16], b) : 0;
    }
    __syncthreads();
    if (i0 < NSB) lhist[i0] = lofs[i0];  // cursors
    if (i1 < NSB) lhist[i1] = lofs[i1];
    __syncthreads();
    for (int i = tid; i < tcnt; i += 512) {
        int e = base + i;
        int d = edst[e], srcv = esrc[e];
        int pos = atomicAdd(&lhist[d >> FSH], 1);
        lsrt[pos] = ((unsigned)(d & (BNODES - 1)) << 17) | (unsigned)srcv;
    }
    __syncthreads();
    // flattened flush: binary search run id, coalesced run-contiguous stores
    for (int i = tid; i < tcnt; i += 512) {
        int lo = 0, hi = NSB - 1;
        while (lo < hi) { int mid = (lo + hi + 1) >> 1; if (lofs[mid] <= i) lo = mid; else hi = mid - 1; }
        pairs[gbase[lo] + (i - lofs[lo])] = lsrt[i];
    }
}

// ---- layer-1 agg: own-bucket LDS sort + shared-exp 4-lane fp16 gather ----
__global__ __launch_bounds__(512) void k_agg1(
    const int* __restrict__ boffs, const unsigned* __restrict__ pairs,
    const float* __restrict__ s1, const float* __restrict__ d1, const __half* __restrict__ h1,
    const float* __restrict__ b1, const float* __restrict__ W2,
    const float* __restrict__ a2s, const float* __restrict__ a2d,
    __half* __restrict__ h2, float* __restrict__ s2, float* __restrict__ d2,
    const unsigned* __restrict__ gmax1p, unsigned* __restrict__ gmax2, int N)
{
    __shared__ unsigned srt[CAP];
    __shared__ float accs[BNODES * 17];
    __shared__ int lcnt[BNODES];
    __shared__ int lofs[BNODES + 1];
    __shared__ float dds[BNODES], mbs[BNODES];
    __shared__ float sW[160], sb[16], sas[16], sad[16];
    __shared__ int wsum[8];
    __shared__ float wm[8];

    int tid = threadIdx.x;
    int fb = blockIdx.x;
    if (tid < 160) sW[tid] = W2[tid];
    if (tid < 16) {
        sb[tid]  = b1[tid];
        sas[tid] = (tid < 10) ? a2s[tid] : 0.f;
        sad[tid] = (tid < 10) ? a2d[tid] : 0.f;
    }
    int node0 = fb << FSH;
    float g0 = fdec(*gmax1p);
    if (tid < BNODES) {
        int n = node0 + tid;
        float dd = (n < N) ? d1[n] : 0.f;
        dds[tid] = dd; mbs[tid] = lrelu(g0 + dd);
        lcnt[tid] = 0;
    }
    __syncthreads();

    int jbeg = boffs[fb], jend = boffs[fb + 1];
    int cnt = jend - jbeg;

    // count pass with register staging (single global read of pairs)
    unsigned pe[PES];
#pragma unroll
    for (int u = 0; u < PES; ++u) {
        int i = tid + u * 512;
        bool ok = (i < cnt);
        pe[u] = ok ? pairs[jbeg + i] : 0u;
        if (ok) atomicAdd(&lcnt[(pe[u] >> 17) & (BNODES - 1)], 1);
    }
    __syncthreads();
    // 128-key scan (padded to 512 threads)
    int c = (tid < BNODES) ? lcnt[tid] : 0;
    int pfx = c;
#pragma unroll
    for (int off = 1; off < 64; off <<= 1) {
        int t = __shfl_up(pfx, off, 64);
        if ((tid & 63) >= off) pfx += t;
    }
    if ((tid & 63) == 63) wsum[tid >> 6] = pfx;
    __syncthreads();
    int carry = 0;
    for (int w = 0; w < (tid >> 6); ++w) carry += wsum[w];
    pfx += carry;
    if (tid < BNODES) { lofs[tid + 1] = pfx; lcnt[tid] = pfx - c; }
    if (tid == 0) lofs[0] = 0;
    __syncthreads();
    int total = lofs[BNODES];

    int gg = tid >> 2, q = tid & 3;      // 128 groups x 4 lanes, 1 node each
    int n = node0 + gg;
    float4 accv; float den;
    if (n < N) {
        float w = __expf(lrelu(s1[n] + dds[gg]) - mbs[gg]);
        float4 hv = ldh4(h1, (size_t)n * 16 + 4 * q);
        accv = make_float4(w * hv.x, w * hv.y, w * hv.z, w * hv.w);
        den = w;
    } else { accv = make_float4(0.f, 0.f, 0.f, 0.f); den = 0.f; }

    if (total <= CAP && cnt <= CAP) {
        // scatter pass from registers -> dst-sorted srcs
#pragma unroll
        for (int u = 0; u < PES; ++u) {
            int i = tid + u * 512;
            if (i < cnt) {
                unsigned p = pe[u];
                int pos = atomicAdd(&lcnt[(p >> 17) & (BNODES - 1)], 1);
                srt[pos] = p & 0x1FFFF;
            }
        }
        __syncthreads();
        // gather: 1 exp/edge (lane q does edge j+q, share via width-4 shfl)
        {
            float dd = dds[gg], mb = mbs[gg];
            int j = lofs[gg], j1 = lofs[gg + 1];
            for (; j + 4 <= j1; j += 4) {
                int e0 = srt[j], e1 = srt[j + 1], e2 = srt[j + 2], e3 = srt[j + 3];
                float4 H0 = ldh4(h1, (size_t)e0 * 16 + 4 * q);
                float4 H1 = ldh4(h1, (size_t)e1 * 16 + 4 * q);
                float4 H2 = ldh4(h1, (size_t)e2 * 16 + 4 * q);
                float4 H3 = ldh4(h1, (size_t)e3 * 16 + 4 * q);
                int eq = srt[j + q];
                float wq = __expf(lrelu(s1[eq] + dd) - mb);
                float w0 = __shfl(wq, 0, 4), w1 = __shfl(wq, 1, 4);
                float w2 = __shfl(wq, 2, 4), w3 = __shfl(wq, 3, 4);
                accv.x += w0 * H0.x + w1 * H1.x + w2 * H2.x + w3 * H3.x;
                accv.y += w0 * H0.y + w1 * H1.y + w2 * H2.y + w3 * H3.y;
                accv.z += w0 * H0.z + w1 * H1.z + w2 * H2.z + w3 * H3.z;
                accv.w += w0 * H0.w + w1 * H1.w + w2 * H2.w + w3 * H3.w;
                den += (w0 + w1) + (w2 + w3);
            }
            for (; j < j1; ++j) {
                int e0 = srt[j];
                float w0 = __expf(lrelu(s1[e0] + dd) - mb);
                float4 H0 = ldh4(h1, (size_t)e0 * 16 + 4 * q);
                accv.x += w0 * H0.x; accv.y += w0 * H0.y;
                accv.z += w0 * H0.z; accv.w += w0 * H0.w;
                den += w0;
            }
        }
        __syncthreads();
    } else {
        // fallback (statistically unreachable)
        for (int i = tid; i < BNODES * 17; i += 512) accs[i] = 0.f;
        __syncthreads();
        for (int i = tid; i < cnt; i += 512) {
            unsigned p = pairs[jbeg + i];
            int src = p & 0x1FFFF, nl = (p >> 17) & (BNODES - 1);
            float w = __expf(lrelu(s1[src] + dds[nl]) - mbs[nl]);
            float4 H = ldh4(h1, (size_t)src * 16 + 4 * q);
            atomicAdd(&accs[nl * 17 + 4 * q + 0], w * H.x);
            atomicAdd(&accs[nl * 17 + 4 * q + 1], w * H.y);
            atomicAdd(&accs[nl * 17 + 4 * q + 2], w * H.z);
            atomicAdd(&accs[nl * 17 + 4 * q + 3], w * H.w);
            if (q == 0) atomicAdd(&accs[nl * 17 + 16], w);
        }
        __syncthreads();
        accv.x += accs[gg * 17 + 4 * q + 0];
        accv.y += accs[gg * 17 + 4 * q + 1];
        accv.z += accs[gg * 17 + 4 * q + 2];
        accv.w += accs[gg * 17 + 4 * q + 3];
        den += accs[gg * 17 + 16];
        __syncthreads();
    }

    // stage accumulators to LDS (stride-17 rows)
    accs[gg * 17 + 4 * q + 0] = accv.x;
    accs[gg * 17 + 4 * q + 1] = accv.y;
    accs[gg * 17 + 4 * q + 2] = accv.z;
    accs[gg * 17 + 4 * q + 3] = accv.w;
    if (q == 0) accs[gg * 17 + 16] = den;
    __syncthreads();

    // epilogue: 32 groups of 16 lanes, 4 nodes each
    int g = tid >> 4, k = tid & 15;
    float sval = -3.4e38f;
#pragma unroll
    for (int qq = 0; qq < 4; ++qq) {
        int nl = g * 4 + qq, nn = node0 + nl;
        if (nn >= N) continue;           // group-uniform
        float inv = 1.f / accs[nl * 17 + 16];
        float o = fmaxf(accs[nl * 17 + k] * inv + sb[k], 0.f);
        float hh = 0.f;
#pragma unroll
        for (int kk = 0; kk < 16; ++kk) {
            float ov = __shfl(o, kk, 16);
            if (k < 10) hh += ov * sW[kk * 10 + k];
        }
        if (k >= 10) hh = 0.f;
        float ts = hh * sas[k];
        float td = hh * sad[k];
#pragma unroll
        for (int off = 1; off < 16; off <<= 1) {
            ts += __shfl_xor(ts, off, 16);
            td += __shfl_xor(td, off, 16);
        }
        h2[(size_t)nn * 16 + k] = __float2half_rn(hh);  // zero-padded cols 10..15
        if (k == 0) { s2[nn] = ts; d2[nn] = td; }
        sval = fmaxf(sval, ts);
    }
    float m = sval;
#pragma unroll
    for (int off = 32; off >= 1; off >>= 1) m = fmaxf(m, __shfl_xor(m, off));
    if ((tid & 63) == 0) wm[tid >> 6] = m;
    __syncthreads();
    if (tid == 0) {
        float bmx = wm[0];
#pragma unroll
        for (int i = 1; i < 8; ++i) bmx = fmaxf(bmx, wm[i]);
        atomicMax(gmax2, fenc(bmx));
    }
}

// ---- layer-2 agg (same structure) + norm/bias + MLP head -> out ----
__global__ __launch_bounds__(512) void k_agg2(
    const int* __restrict__ boffs, const unsigned* __restrict__ pairs,
    const float* __restrict__ s2, const float* __restrict__ d2, const __half* __restrict__ h2,
    const float* __restrict__ b2, const float* __restrict__ Wl1, const float* __restrict__ bl1,
    const float* __restrict__ Wl2, const float* __restrict__ bl2,
    const unsigned* __restrict__ gmax2p, float* __restrict__ out, int N)
{
    __shared__ unsigned srt[CAP];
    __shared__ float accs[BNODES * 17];
    __shared__ int lcnt[BNODES];
    __shared__ int lofs[BNODES + 1];
    __shared__ float dds[BNODES], mbs[BNODES];
    __shared__ float sW1[100], sb1[16], sW2[16], sb2g[16];
    __shared__ float sbl2;
    __shared__ int wsum[8];

    int tid = threadIdx.x;
    int fb = blockIdx.x;
    if (tid < 100) sW1[tid] = Wl1[tid];
    if (tid < 16) {
        sb1[tid]  = (tid < 10) ? bl1[tid] : 0.f;
        sW2[tid]  = (tid < 10) ? Wl2[tid] : 0.f;
        sb2g[tid] = (tid < 10) ? b2[tid]  : 0.f;
    }
    if (tid == 0) sbl2 = bl2[0];
    int node0 = fb << FSH;
    float g0 = fdec(*gmax2p);
    if (tid < BNODES) {
        int n = node0 + tid;
        float dd = (n < N) ? d2[n] : 0.f;
        dds[tid] = dd; mbs[tid] = lrelu(g0 + dd);
        lcnt[tid] = 0;
    }
    __syncthreads();

    int jbeg = boffs[fb], jend = boffs[fb + 1];
    int cnt = jend - jbeg;

    unsigned pe[PES];
#pragma unroll
    for (int u = 0; u < PES; ++u) {
        int i = tid + u * 512;
        bool ok = (i < cnt);
        pe[u] = ok ? pairs[jbeg + i] : 0u;
        if (ok) atomicAdd(&lcnt[(pe[u] >> 17) & (BNODES - 1)], 1);
    }
    __syncthreads();
    int c = (tid < BNODES) ? lcnt[tid] : 0;
    int pfx = c;
#pragma unroll
    for (int off = 1; off < 64; off <<= 1) {
        int t = __shfl_up(pfx, off, 64);
        if ((tid & 63) >= off) pfx += t;
    }
    if ((tid & 63) == 63) wsum[tid >> 6] = pfx;
    __syncthreads();
    int carry = 0;
    for (int w = 0; w < (tid >> 6); ++w) carry += wsum[w];
    pfx += carry;
    if (tid < BNODES) { lofs[tid + 1] = pfx; lcnt[tid] = pfx - c; }
    if (tid == 0) lofs[0] = 0;
    __syncthreads();
    int total = lofs[BNODES];

    int gg = tid >> 2, q = tid & 3;
    int n = node0 + gg;
    float4 accv; float den;
    if (n < N) {
        float w = __expf(lrelu(s2[n] + dds[gg]) - mbs[gg]);
        float4 hv = ldh4(h2, (size_t)n * 16 + 4 * q);   // zero-padded
        accv = make_float4(w * hv.x, w * hv.y, w * hv.z, w * hv.w);
        den = w;
    } else { accv = make_float4(0.f, 0.f, 0.f, 0.f); den = 0.f; }

    if (total <= CAP && cnt <= CAP) {
#pragma unroll
        for (int u = 0; u < PES; ++u) {
            int i = tid + u * 512;
            if (i < cnt) {
                unsigned p = pe[u];
                int pos = atomicAdd(&lcnt[(p >> 17) & (BNODES - 1)], 1);
                srt[pos] = p & 0x1FFFF;
            }
        }
        __syncthreads();
        {
            float dd = dds[gg], mb = mbs[gg];
            int j = lofs[gg], j1 = lofs[gg + 1];
            for (; j + 4 <= j1; j += 4) {
                int e0 = srt[j], e1 = srt[j + 1], e2 = srt[j + 2], e3 = srt[j + 3];
                float4 H0 = ldh4(h2, (size_t)e0 * 16 + 4 * q);
                float4 H1 = ldh4(h2, (size_t)e1 * 16 + 4 * q);
                float4 H2 = ldh4(h2, (size_t)e2 * 16 + 4 * q);
                float4 H3 = ldh4(h2, (size_t)e3 * 16 + 4 * q);
                int eq = srt[j + q];
                float wq = __expf(lrelu(s2[eq] + dd) - mb);
                float w0 = __shfl(wq, 0, 4), w1 = __shfl(wq, 1, 4);
                float w2 = __shfl(wq, 2, 4), w3 = __shfl(wq, 3, 4);
                accv.x += w0 * H0.x + w1 * H1.x + w2 * H2.x + w3 * H3.x;
                accv.y += w0 * H0.y + w1 * H1.y + w2 * H2.y + w3 * H3.y;
                accv.z += w0 * H0.z + w1 * H1.z + w2 * H2.z + w3 * H3.z;
                accv.w += w0 * H0.w + w1 * H1.w + w2 * H2.w + w3 * H3.w;
                den += (w0 + w1) + (w2 + w3);
            }
            for (; j < j1; ++j) {
                int e0 = srt[j];
                float w0 = __expf(lrelu(s2[e0] + dd) - mb);
                float4 H0 = ldh4(h2, (size_t)e0 * 16 + 4 * q);
                accv.x += w0 * H0.x; accv.y += w0 * H0.y;
                accv.z += w0 * H0.z; accv.w += w0 * H0.w;
                den += w0;
            }
        }
        __syncthreads();
    } else {
        for (int i = tid; i < BNODES * 17; i += 512) accs[i] = 0.f;
        __syncthreads();
        for (int i = tid; i < cnt; i += 512) {
            unsigned p = pairs[jbeg + i];
            int src = p & 0x1FFFF, nl = (p >> 17) & (BNODES - 1);
            float w = __expf(lrelu(s2[src] + dds[nl]) - mbs[nl]);
            float4 H = ldh4(h2, (size_t)src * 16 + 4 * q);
            atomicAdd(&accs[nl * 17 + 4 * q + 0], w * H.x);
            atomicAdd(&accs[nl * 17 + 4 * q + 1], w * H.y);
            atomicAdd(&accs[nl * 17 + 4 * q + 2], w * H.z);
            atomicAdd(&accs[nl * 17 + 4 * q + 3], w * H.w);
            if (q == 0) atomicAdd(&accs[nl * 17 + 16], w);
        }
        __syncthreads();
        accv.x += accs[gg * 17 + 4 * q + 0];
        accv.y += accs[gg * 17 + 4 * q + 1];
        accv.z += accs[gg * 17 + 4 * q + 2];
        accv.w += accs[gg * 17 + 4 * q + 3];
        den += accs[gg * 17 + 16];
        __syncthreads();
    }

    accs[gg * 17 + 4 * q + 0] = accv.x;
    accs[gg * 17 + 4 * q + 1] = accv.y;
    accs[gg * 17 + 4 * q + 2] = accv.z;
    accs[gg * 17 + 4 * q + 3] = accv.w;
    if (q == 0) accs[gg * 17 + 16] = den;
    __syncthreads();

    int g = tid >> 4, k = tid & 15;
    bool fk = k < 10;
#pragma unroll
    for (int qq = 0; qq < 4; ++qq) {
        int nl = g * 4 + qq, nn = node0 + nl;
        if (nn >= N) continue;           // group-uniform
        float inv = 1.f / accs[nl * 17 + 16];
        float o = fk ? accs[nl * 17 + k] * inv + sb2g[k] : 0.f;
        float v = sb1[k];
#pragma unroll
        for (int kk = 0; kk < 10; ++kk) {
            float ov = __shfl(o, kk, 16);
            if (fk) v += ov * sW1[kk * 10 + k];
        }
        float t = fmaxf(v, 0.f);
        float cc = t * sW2[k];           // zero for k>=10
#pragma unroll
        for (int off = 1; off < 16; off <<= 1) cc += __shfl_xor(cc, off, 16);
        if (k == 0) out[nn] = cc + sbl2;
    }
}

extern "C" void kernel_launch(void* const* d_in, const int* in_sizes, int n_in,
                              void* d_out, int out_size, void* d_ws, size_t ws_size,
                              hipStream_t stream)
{
    const float* x   = (const float*)d_in[0];
    const int*   ei  = (const int*)  d_in[1];   // [2][E] int32
    const float* W1  = (const float*)d_in[2];
    const float* a1s = (const float*)d_in[3];
    const float* a1d = (const float*)d_in[4];
    const float* b1  = (const float*)d_in[5];
    const float* W2  = (const float*)d_in[6];
    const float* a2s = (const float*)d_in[7];
    const float* a2d = (const float*)d_in[8];
    const float* b2  = (const float*)d_in[9];
    const float* Wl1 = (const float*)d_in[10];
    const float* bl1 = (const float*)d_in[11];
    const float* Wl2 = (const float*)d_in[12];
    const float* bl2 = (const float*)d_in[13];

    int N = in_sizes[0] / 128;
    int E = in_sizes[1] / 2;
    const int* ei_src = ei;
    const int* ei_dst = ei + E;
    int NSB = (N + BNODES - 1) >> FSH;       // 782 buckets (<= NSBMAX)

    size_t Np = ((size_t)N + 3) & ~(size_t)3;
    // floats: 16 hdr + h1(Np*8) + s1 + d1 + h2(Np*8) + s2 + d2 = 16 + 20*Np
    size_t need_bytes = (16 + Np * 20) * 4 + ((size_t)NSB * 18 + 1) * 4 + (size_t)E * 4;
    if (ws_size < need_bytes) return;  // degrade to wrong-answer, never fault

    float*    ws    = (float*)d_ws;
    unsigned* gmax1 = (unsigned*)d_ws;       // [0]
    unsigned* gmax2 = gmax1 + 1;             // [1]
    __half* h1 = (__half*)(ws + 16);         // Np*16 halves
    float* s1 = ws + 16 + Np * 8;            // Np
    float* d1 = s1 + Np;                     // Np
    __half* h2 = (__half*)(d1 + Np);         // Np*16 halves (cols 10..15 zero)
    float* s2 = (float*)(h2) + Np * 8;       // Np
    float* d2 = s2 + Np;                     // Np
    int* chist  = (int*)(d2 + Np);           // NSB
    int* cboffs = chist + NSB;               // NSB+1
    int* ccur   = cboffs + NSB + 1;          // NSB*16 (1 cursor per 64B)
    unsigned* pairs = (unsigned*)(ccur + (size_t)NSB * 16);  // E

    hipLaunchKernelGGL(k_init, dim3((NSB + 255) / 256), dim3(256), 0, stream, gmax1, chist, NSB);
    hipLaunchKernelGGL(k_gemm1, dim3((N + 63) / 64), dim3(256), 0, stream,
                       x, W1, a1s, a1d, h1, s1, d1, gmax1, N);
    hipLaunchKernelGGL(k_chist, dim3(256), dim3(256), 0, stream, ei_dst, chist, E, NSB);
    hipLaunchKernelGGL(k_cboffs, dim3(1), dim3(512), 0, stream, chist, cboffs, ccur, NSB, E);
    hipLaunchKernelGGL(k_csplit, dim3((E + TILE - 1) / TILE), dim3(512), 0, stream,
                       ei_src, ei_dst, ccur, pairs, E, NSB);
    hipLaunchKernelGGL(k_agg1, dim3(NSB), dim3(512), 0, stream,
                       cboffs, pairs, s1, d1, h1, b1, W2, a2s, a2d, h2, s2, d2,
                       gmax1, gmax2, N);
    hipLaunchKernelGGL(k_agg2, dim3(NSB), dim3(512), 0, stream,
                       cboffs, pairs, s2, d2, h2, b2, Wl1, bl1, Wl2, bl2,
                       gmax2, (float*)d_out, N);
}

// Round 11
// 276.399 us; speedup vs baseline: 3.6512x; 1.0591x over previous
//
#include <hip/hip_runtime.h>
#include <hip/hip_fp16.h>

// GAT (2 layers, heads=1) + 2-layer MLP head. N=100000, E=3200000, D=128.
// R11: fixed-capacity per-bucket regions (CAPB) remove the global histogram +
// offset-scan kernels entirely (5-kernel pipeline). Agg keeps R10's proven
// gather (coalesced 32B fp16 rows, 1 exp/edge); overflow -> full-rescan
// fallback keeps arbitrary inputs correct (never triggers for this dist).
// Softmax stabilization uses a GLOBAL upper bound m̄_i = leaky(gmax_asrc + adst_i)
// (valid since leaky_relu is monotone); alpha is mathematically unchanged.

#define NEG 0.2f
#define FSH 7
#define BNODES 128           // nodes per bucket
#define NSBMAX 1024          // >= ceil(100000/128)=782
#define CAPB 4608            // per-bucket region capacity (mean 4096, +8 sigma)
#define TILE 8192            // edges per csplit block
#define PES 9                // ceil(CAPB/512) register-staged pairs per thread

__device__ __forceinline__ float lrelu(float x) { return x > 0.0f ? x : NEG * x; }

__device__ __forceinline__ unsigned fenc(float f) {
    unsigned u = __float_as_uint(f);
    return (u & 0x80000000u) ? ~u : (u | 0x80000000u);
}
__device__ __forceinline__ float fdec(unsigned e) {
    return (e & 0x80000000u) ? __uint_as_float(e & 0x7FFFFFFFu) : __uint_as_float(~e);
}

// load 4 consecutive halves as float4 (8B load)
__device__ __forceinline__ float4 ldh4(const __half* h, size_t off) {
    uint2 u = *(const uint2*)(h + off);
    __half2 a = *(__half2*)&u.x, b = *(__half2*)&u.y;
    float2 fa = __half22float2(a), fb = __half22float2(b);
    return make_float4(fa.x, fa.y, fb.x, fb.y);
}

// init gmax + per-bucket region cursors (absolute positions)
__global__ __launch_bounds__(256) void k_init(unsigned* g, int* bcur, int NSB) {
    int i = blockIdx.x * 256 + threadIdx.x;
    if (i < NSB) bcur[i * 16] = i * CAPB;
    if (i < 2) g[i] = 0u;
}

// K1: h1 = x @ W1 (128->16) [fp16 out], s1 = h1·a1s, d1 = h1·a1d, gmax1 = max(s1)
__global__ __launch_bounds__(256) void k_gemm1(
    const float* __restrict__ x, const float* __restrict__ W1,
    const float* __restrict__ a1s, const float* __restrict__ a1d,
    __half* __restrict__ h1, float* __restrict__ s1, float* __restrict__ d1,
    unsigned* __restrict__ gmax, int N)
{
    __shared__ float sW[128 * 16];
    __shared__ float sx[64 * 132];
    __shared__ float wm[4];
    int tid = threadIdx.x;
    for (int i = tid; i < 2048; i += 256) sW[i] = W1[i];
    int node0 = blockIdx.x * 64;
    for (int i = tid; i < 64 * 32; i += 256) {
        int row = i >> 5, c4 = i & 31;
        int n = node0 + row;
        float4 v = make_float4(0.f, 0.f, 0.f, 0.f);
        if (n < N) v = ((const float4*)x)[(size_t)n * 32 + c4];
        *(float4*)&sx[row * 132 + c4 * 4] = v;
    }
    __syncthreads();

    int node = node0 + (tid >> 2);
    int grp  = tid & 3;
    const float* xr = &sx[(tid >> 2) * 132];
    float4 acc = make_float4(0.f, 0.f, 0.f, 0.f);
#pragma unroll 8
    for (int j = 0; j < 128; ++j) {
        float xv = xr[j];
        float4 w = *(const float4*)&sW[j * 16 + grp * 4];
        acc.x += xv * w.x; acc.y += xv * w.y; acc.z += xv * w.z; acc.w += xv * w.w;
    }
    float4 as = ((const float4*)a1s)[grp];
    float4 ad = ((const float4*)a1d)[grp];
    float sv = acc.x * as.x + acc.y * as.y + acc.z * as.z + acc.w * as.w;
    float dv = acc.x * ad.x + acc.y * ad.y + acc.z * ad.z + acc.w * ad.w;
    sv += __shfl_xor(sv, 1); sv += __shfl_xor(sv, 2);
    dv += __shfl_xor(dv, 1); dv += __shfl_xor(dv, 2);
    if (node < N) {
        __half2 p0 = __floats2half2_rn(acc.x, acc.y);
        __half2 p1 = __floats2half2_rn(acc.z, acc.w);
        uint2 u; u.x = *(unsigned*)&p0; u.y = *(unsigned*)&p1;
        *(uint2*)&h1[(size_t)node * 16 + grp * 4] = u;
        if (grp == 0) { s1[node] = sv; d1[node] = dv; }
    }
    float m = (node < N) ? sv : -3.4e38f;
#pragma unroll
    for (int off = 32; off >= 1; off >>= 1) m = fmaxf(m, __shfl_xor(m, off));
    if ((tid & 63) == 0) wm[tid >> 6] = m;
    __syncthreads();
    if (tid == 0) {
        float b = fmaxf(fmaxf(wm[0], wm[1]), fmaxf(wm[2], wm[3]));
        atomicMax(gmax, fenc(b));
    }
}

// split: LDS-sort a tile of 8192 edges by 128-node bucket, flush run-granular
// into fixed per-bucket regions; elements past a region's limit are dropped
// (bucket flagged by cursor > limit; agg rescans such buckets from the source).
__global__ __launch_bounds__(512) void k_csplit(
    const int* __restrict__ esrc, const int* __restrict__ edst,
    int* __restrict__ bcur, unsigned* __restrict__ pairs, int E, int NSB)
{
    __shared__ unsigned lsrt[TILE];
    __shared__ int lhist[NSBMAX];        // counts -> cursors
    __shared__ int lofs[NSBMAX];         // exclusive run starts
    __shared__ int gbase[NSBMAX];
    __shared__ int wsum[8];
    int tid = threadIdx.x;
    int base = blockIdx.x * TILE;
    int tcnt = min(TILE, E - base);
    for (int i = tid; i < NSB; i += 512) lhist[i] = 0;
    __syncthreads();
    for (int i = tid; i < tcnt; i += 512)
        atomicAdd(&lhist[edst[base + i] >> FSH], 1);
    __syncthreads();
    int i0 = 2 * tid, i1 = i0 + 1;
    int a = (i0 < NSB) ? lhist[i0] : 0;
    int b = (i1 < NSB) ? lhist[i1] : 0;
    int s = a + b, pfx = s;
#pragma unroll
    for (int off = 1; off < 64; off <<= 1) {
        int t = __shfl_up(pfx, off, 64);
        if ((tid & 63) >= off) pfx += t;
    }
    if ((tid & 63) == 63) wsum[tid >> 6] = pfx;
    __syncthreads();
    int carry = 0;
    for (int w = 0; w < (tid >> 6); ++w) carry += wsum[w];
    int excl = pfx + carry - s;
    if (i0 < NSB) {
        lofs[i0] = excl;
        gbase[i0] = a ? atomicAdd(&bcur[i0 * 16], a) : 0;
    }
    if (i1 < NSB) {
        lofs[i1] = excl + a;
        gbase[i1] = b ? atomicAdd(&bcur[i1 * 16], b) : 0;
    }
    __syncthreads();
    if (i0 < NSB) lhist[i0] = lofs[i0];  // cursors
    if (i1 < NSB) lhist[i1] = lofs[i1];
    __syncthreads();
    for (int i = tid; i < tcnt; i += 512) {
        int e = base + i;
        int d = edst[e], srcv = esrc[e];
        int pos = atomicAdd(&lhist[d >> FSH], 1);
        lsrt[pos] = ((unsigned)(d & (BNODES - 1)) << 17) | (unsigned)srcv;
    }
    __syncthreads();
    // flattened flush: binary search run id, coalesced run-contiguous stores
    for (int i = tid; i < tcnt; i += 512) {
        int lo = 0, hi = NSB - 1;
        while (lo < hi) { int mid = (lo + hi + 1) >> 1; if (lofs[mid] <= i) lo = mid; else hi = mid - 1; }
        int gp = gbase[lo] + (i - lofs[lo]);
        if (gp < (lo + 1) * CAPB) pairs[gp] = lsrt[i];
    }
}

// ---- layer-1 agg: own-region LDS sort + shared-exp 4-lane fp16 gather ----
__global__ __launch_bounds__(512) void k_agg1(
    const int* __restrict__ bcur, const unsigned* __restrict__ pairs,
    const int* __restrict__ esrc, const int* __restrict__ edst,
    const float* __restrict__ s1, const float* __restrict__ d1, const __half* __restrict__ h1,
    const float* __restrict__ b1, const float* __restrict__ W2,
    const float* __restrict__ a2s, const float* __restrict__ a2d,
    __half* __restrict__ h2, float* __restrict__ s2, float* __restrict__ d2,
    const unsigned* __restrict__ gmax1p, unsigned* __restrict__ gmax2, int N, int E)
{
    __shared__ unsigned srt[CAPB];
    __shared__ float accs[BNODES * 17];
    __shared__ int lcnt[BNODES];
    __shared__ int lofs[BNODES + 1];
    __shared__ float dds[BNODES], mbs[BNODES];
    __shared__ float sW[160], sb[16], sas[16], sad[16];
    __shared__ int wsum[8];
    __shared__ float wm[8];

    int tid = threadIdx.x;
    int fb = blockIdx.x;
    if (tid < 160) sW[tid] = W2[tid];
    if (tid < 16) {
        sb[tid]  = b1[tid];
        sas[tid] = (tid < 10) ? a2s[tid] : 0.f;
        sad[tid] = (tid < 10) ? a2d[tid] : 0.f;
    }
    int node0 = fb << FSH;
    float g0 = fdec(*gmax1p);
    if (tid < BNODES) {
        int n = node0 + tid;
        float dd = (n < N) ? d1[n] : 0.f;
        dds[tid] = dd; mbs[tid] = lrelu(g0 + dd);
        lcnt[tid] = 0;
    }
    __syncthreads();

    int rbase = fb * CAPB;
    int cnt = bcur[fb * 16] - rbase;     // block-uniform; > CAPB means overflow
    int gg = tid >> 2, q = tid & 3;      // 128 groups x 4 lanes, 1 node each

    if (cnt <= CAPB) {
        // count pass with register staging (single global read of pairs)
        unsigned pe[PES];
#pragma unroll
        for (int u = 0; u < PES; ++u) {
            int i = tid + u * 512;
            bool ok = (i < cnt);
            pe[u] = ok ? pairs[rbase + i] : 0u;
            if (ok) atomicAdd(&lcnt[(pe[u] >> 17) & (BNODES - 1)], 1);
        }
        __syncthreads();
        // 128-key scan (padded to 512 threads)
        int c = (tid < BNODES) ? lcnt[tid] : 0;
        int pfx = c;
#pragma unroll
        for (int off = 1; off < 64; off <<= 1) {
            int t = __shfl_up(pfx, off, 64);
            if ((tid & 63) >= off) pfx += t;
        }
        if ((tid & 63) == 63) wsum[tid >> 6] = pfx;
        __syncthreads();
        int carry = 0;
        for (int w = 0; w < (tid >> 6); ++w) carry += wsum[w];
        pfx += carry;
        if (tid < BNODES) { lofs[tid + 1] = pfx; lcnt[tid] = pfx - c; }
        if (tid == 0) lofs[0] = 0;
        __syncthreads();
        // scatter pass from registers -> dst-sorted srcs
#pragma unroll
        for (int u = 0; u < PES; ++u) {
            int i = tid + u * 512;
            if (i < cnt) {
                unsigned p = pe[u];
                int pos = atomicAdd(&lcnt[(p >> 17) & (BNODES - 1)], 1);
                srt[pos] = p & 0x1FFFF;
            }
        }
        __syncthreads();

        // self-loop init + register gather (1 exp/edge via width-4 shfl)
        int n = node0 + gg;
        float4 accv; float den;
        if (n < N) {
            float w = __expf(lrelu(s1[n] + dds[gg]) - mbs[gg]);
            float4 hv = ldh4(h1, (size_t)n * 16 + 4 * q);
            accv = make_float4(w * hv.x, w * hv.y, w * hv.z, w * hv.w);
            den = w;
        } else { accv = make_float4(0.f, 0.f, 0.f, 0.f); den = 0.f; }
        {
            float dd = dds[gg], mb = mbs[gg];
            int j = lofs[gg], j1 = lofs[gg + 1];
            for (; j + 4 <= j1; j += 4) {
                int e0 = srt[j], e1 = srt[j + 1], e2 = srt[j + 2], e3 = srt[j + 3];
                float4 H0 = ldh4(h1, (size_t)e0 * 16 + 4 * q);
                float4 H1 = ldh4(h1, (size_t)e1 * 16 + 4 * q);
                float4 H2 = ldh4(h1, (size_t)e2 * 16 + 4 * q);
                float4 H3 = ldh4(h1, (size_t)e3 * 16 + 4 * q);
                int eq = srt[j + q];
                float wq = __expf(lrelu(s1[eq] + dd) - mb);
                float w0 = __shfl(wq, 0, 4), w1 = __shfl(wq, 1, 4);
                float w2 = __shfl(wq, 2, 4), w3 = __shfl(wq, 3, 4);
                accv.x += w0 * H0.x + w1 * H1.x + w2 * H2.x + w3 * H3.x;
                accv.y += w0 * H0.y + w1 * H1.y + w2 * H2.y + w3 * H3.y;
                accv.z += w0 * H0.z + w1 * H1.z + w2 * H2.z + w3 * H3.z;
                accv.w += w0 * H0.w + w1 * H1.w + w2 * H2.w + w3 * H3.w;
                den += (w0 + w1) + (w2 + w3);
            }
            for (; j < j1; ++j) {
                int e0 = srt[j];
                float w0 = __expf(lrelu(s1[e0] + dd) - mb);
                float4 H0 = ldh4(h1, (size_t)e0 * 16 + 4 * q);
                accv.x += w0 * H0.x; accv.y += w0 * H0.y;
                accv.z += w0 * H0.z; accv.w += w0 * H0.w;
                den += w0;
            }
        }
        // stage accumulators to LDS (stride-17 rows)
        accs[gg * 17 + 4 * q + 0] = accv.x;
        accs[gg * 17 + 4 * q + 1] = accv.y;
        accs[gg * 17 + 4 * q + 2] = accv.z;
        accs[gg * 17 + 4 * q + 3] = accv.w;
        if (q == 0) accs[gg * 17 + 16] = den;
        __syncthreads();
    } else {
        // overflow: region incomplete -> full rescan of source edges (never-path)
        for (int i = tid; i < BNODES * 17; i += 512) accs[i] = 0.f;
        __syncthreads();
        if (tid < BNODES) {
            int n = node0 + tid;
            if (n < N) {
                float w = __expf(lrelu(s1[n] + dds[tid]) - mbs[tid]);
#pragma unroll
                for (int t = 0; t < 16; ++t)
                    accs[tid * 17 + t] = w * __half2float(h1[(size_t)n * 16 + t]);
                accs[tid * 17 + 16] = w;
            }
        }
        __syncthreads();
        for (int i = tid; i < E; i += 512) {
            int d = edst[i];
            if ((d >> FSH) != fb) continue;
            int nl = d & (BNODES - 1), src = esrc[i];
            float w = __expf(lrelu(s1[src] + dds[nl]) - mbs[nl]);
#pragma unroll
            for (int t = 0; t < 16; ++t)
                atomicAdd(&accs[nl * 17 + t], w * __half2float(h1[(size_t)src * 16 + t]));
            atomicAdd(&accs[nl * 17 + 16], w);
        }
        __syncthreads();
    }

    // epilogue: 32 groups of 16 lanes, 4 nodes each
    int g = tid >> 4, k = tid & 15;
    float sval = -3.4e38f;
#pragma unroll
    for (int qq = 0; qq < 4; ++qq) {
        int nl = g * 4 + qq, nn = node0 + nl;
        if (nn >= N) continue;           // group-uniform
        float inv = 1.f / accs[nl * 17 + 16];
        float o = fmaxf(accs[nl * 17 + k] * inv + sb[k], 0.f);
        float hh = 0.f;
#pragma unroll
        for (int kk = 0; kk < 16; ++kk) {
            float ov = __shfl(o, kk, 16);
            if (k < 10) hh += ov * sW[kk * 10 + k];
        }
        if (k >= 10) hh = 0.f;
        float ts = hh * sas[k];
        float td = hh * sad[k];
#pragma unroll
        for (int off = 1; off < 16; off <<= 1) {
            ts += __shfl_xor(ts, off, 16);
            td += __shfl_xor(td, off, 16);
        }
        h2[(size_t)nn * 16 + k] = __float2half_rn(hh);  // zero-padded cols 10..15
        if (k == 0) { s2[nn] = ts; d2[nn] = td; }
        sval = fmaxf(sval, ts);
    }
    float m = sval;
#pragma unroll
    for (int off = 32; off >= 1; off >>= 1) m = fmaxf(m, __shfl_xor(m, off));
    if ((tid & 63) == 0) wm[tid >> 6] = m;
    __syncthreads();
    if (tid == 0) {
        float bmx = wm[0];
#pragma unroll
        for (int i = 1; i < 8; ++i) bmx = fmaxf(bmx, wm[i]);
        atomicMax(gmax2, fenc(bmx));
    }
}

// ---- layer-2 agg (same structure) + norm/bias + MLP head -> out ----
__global__ __launch_bounds__(512) void k_agg2(
    const int* __restrict__ bcur, const unsigned* __restrict__ pairs,
    const int* __restrict__ esrc, const int* __restrict__ edst,
    const float* __restrict__ s2, const float* __restrict__ d2, const __half* __restrict__ h2,
    const float* __restrict__ b2, const float* __restrict__ Wl1, const float* __restrict__ bl1,
    const float* __restrict__ Wl2, const float* __restrict__ bl2,
    const unsigned* __restrict__ gmax2p, float* __restrict__ out, int N, int E)
{
    __shared__ unsigned srt[CAPB];
    __shared__ float accs[BNODES * 17];
    __shared__ int lcnt[BNODES];
    __shared__ int lofs[BNODES + 1];
    __shared__ float dds[BNODES], mbs[BNODES];
    __shared__ float sW1[100], sb1[16], sW2[16], sb2g[16];
    __shared__ float sbl2;
    __shared__ int wsum[8];

    int tid = threadIdx.x;
    int fb = blockIdx.x;
    if (tid < 100) sW1[tid] = Wl1[tid];
    if (tid < 16) {
        sb1[tid]  = (tid < 10) ? bl1[tid] : 0.f;
        sW2[tid]  = (tid < 10) ? Wl2[tid] : 0.f;
        sb2g[tid] = (tid < 10) ? b2[tid]  : 0.f;
    }
    if (tid == 0) sbl2 = bl2[0];
    int node0 = fb << FSH;
    float g0 = fdec(*gmax2p);
    if (tid < BNODES) {
        int n = node0 + tid;
        float dd = (n < N) ? d2[n] : 0.f;
        dds[tid] = dd; mbs[tid] = lrelu(g0 + dd);
        lcnt[tid] = 0;
    }
    __syncthreads();

    int rbase = fb * CAPB;
    int cnt = bcur[fb * 16] - rbase;
    int gg = tid >> 2, q = tid & 3;

    if (cnt <= CAPB) {
        unsigned pe[PES];
#pragma unroll
        for (int u = 0; u < PES; ++u) {
            int i = tid + u * 512;
            bool ok = (i < cnt);
            pe[u] = ok ? pairs[rbase + i] : 0u;
            if (ok) atomicAdd(&lcnt[(pe[u] >> 17) & (BNODES - 1)], 1);
        }
        __syncthreads();
        int c = (tid < BNODES) ? lcnt[tid] : 0;
        int pfx = c;
#pragma unroll
        for (int off = 1; off < 64; off <<= 1) {
            int t = __shfl_up(pfx, off, 64);
            if ((tid & 63) >= off) pfx += t;
        }
        if ((tid & 63) == 63) wsum[tid >> 6] = pfx;
        __syncthreads();
        int carry = 0;
        for (int w = 0; w < (tid >> 6); ++w) carry += wsum[w];
        pfx += carry;
        if (tid < BNODES) { lofs[tid + 1] = pfx; lcnt[tid] = pfx - c; }
        if (tid == 0) lofs[0] = 0;
        __syncthreads();
#pragma unroll
        for (int u = 0; u < PES; ++u) {
            int i = tid + u * 512;
            if (i < cnt) {
                unsigned p = pe[u];
                int pos = atomicAdd(&lcnt[(p >> 17) & (BNODES - 1)], 1);
                srt[pos] = p & 0x1FFFF;
            }
        }
        __syncthreads();

        int n = node0 + gg;
        float4 accv; float den;
        if (n < N) {
            float w = __expf(lrelu(s2[n] + dds[gg]) - mbs[gg]);
            float4 hv = ldh4(h2, (size_t)n * 16 + 4 * q);   // zero-padded
            accv = make_float4(w * hv.x, w * hv.y, w * hv.z, w * hv.w);
            den = w;
        } else { accv = make_float4(0.f, 0.f, 0.f, 0.f); den = 0.f; }
        {
            float dd = dds[gg], mb = mbs[gg];
            int j = lofs[gg], j1 = lofs[gg + 1];
            for (; j + 4 <= j1; j += 4) {
                int e0 = srt[j], e1 = srt[j + 1], e2 = srt[j + 2], e3 = srt[j + 3];
                float4 H0 = ldh4(h2, (size_t)e0 * 16 + 4 * q);
                float4 H1 = ldh4(h2, (size_t)e1 * 16 + 4 * q);
                float4 H2 = ldh4(h2, (size_t)e2 * 16 + 4 * q);
                float4 H3 = ldh4(h2, (size_t)e3 * 16 + 4 * q);
                int eq = srt[j + q];
                float wq = __expf(lrelu(s2[eq] + dd) - mb);
                float w0 = __shfl(wq, 0, 4), w1 = __shfl(wq, 1, 4);
                float w2 = __shfl(wq, 2, 4), w3 = __shfl(wq, 3, 4);
                accv.x += w0 * H0.x + w1 * H1.x + w2 * H2.x + w3 * H3.x;
                accv.y += w0 * H0.y + w1 * H1.y + w2 * H2.y + w3 * H3.y;
                accv.z += w0 * H0.z + w1 * H1.z + w2 * H2.z + w3 * H3.z;
                accv.w += w0 * H0.w + w1 * H1.w + w2 * H2.w + w3 * H3.w;
                den += (w0 + w1) + (w2 + w3);
            }
            for (; j < j1; ++j) {
                int e0 = srt[j];
                float w0 = __expf(lrelu(s2[e0] + dd) - mb);
                float4 H0 = ldh4(h2, (size_t)e0 * 16 + 4 * q);
                accv.x += w0 * H0.x; accv.y += w0 * H0.y;
                accv.z += w0 * H0.z; accv.w += w0 * H0.w;
                den += w0;
            }
        }
        accs[gg * 17 + 4 * q + 0] = accv.x;
        accs[gg * 17 + 4 * q + 1] = accv.y;
        accs[gg * 17 + 4 * q + 2] = accv.z;
        accs[gg * 17 + 4 * q + 3] = accv.w;
        if (q == 0) accs[gg * 17 + 16] = den;
        __syncthreads();
    } else {
        for (int i = tid; i < BNODES * 17; i += 512) accs[i] = 0.f;
        __syncthreads();
        if (tid < BNODES) {
            int n = node0 + tid;
            if (n < N) {
                float w = __expf(lrelu(s2[n] + dds[tid]) - mbs[tid]);
#pragma unroll
                for (int t = 0; t < 16; ++t)
                    accs[tid * 17 + t] = w * __half2float(h2[(size_t)n * 16 + t]);
                accs[tid * 17 + 16] = w;
            }
        }
        __syncthreads();
        for (int i = tid; i < E; i += 512) {
            int d = edst[i];
            if ((d >> FSH) != fb) continue;
            int nl = d & (BNODES - 1), src = esrc[i];
            float w = __expf(lrelu(s2[src] + dds[nl]) - mbs[nl]);
#pragma unroll
            for (int t = 0; t < 16; ++t)
                atomicAdd(&accs[nl * 17 + t], w * __half2float(h2[(size_t)src * 16 + t]));
            atomicAdd(&accs[nl * 17 + 16], w);
        }
        __syncthreads();
    }

    int g = tid >> 4, k = tid & 15;
    bool fk = k < 10;
#pragma unroll
    for (int qq = 0; qq < 4; ++qq) {
        int nl = g * 4 + qq, nn = node0 + nl;
        if (nn >= N) continue;           // group-uniform
        float inv = 1.f / accs[nl * 17 + 16];
        float o = fk ? accs[nl * 17 + k] * inv + sb2g[k] : 0.f;
        float v = sb1[k];
#pragma unroll
        for (int kk = 0; kk < 10; ++kk) {
            float ov = __shfl(o, kk, 16);
            if (fk) v += ov * sW1[kk * 10 + k];
        }
        float t = fmaxf(v, 0.f);
        float cc = t * sW2[k];           // zero for k>=10
#pragma unroll
        for (int off = 1; off < 16; off <<= 1) cc += __shfl_xor(cc, off, 16);
        if (k == 0) out[nn] = cc + sbl2;
    }
}

extern "C" void kernel_launch(void* const* d_in, const int* in_sizes, int n_in,
                              void* d_out, int out_size, void* d_ws, size_t ws_size,
                              hipStream_t stream)
{
    const float* x   = (const float*)d_in[0];
    const int*   ei  = (const int*)  d_in[1];   // [2][E] int32
    const float* W1  = (const float*)d_in[2];
    const float* a1s = (const float*)d_in[3];
    const float* a1d = (const float*)d_in[4];
    const float* b1  = (const float*)d_in[5];
    const float* W2  = (const float*)d_in[6];
    const float* a2s = (const float*)d_in[7];
    const float* a2d = (const float*)d_in[8];
    const float* b2  = (const float*)d_in[9];
    const float* Wl1 = (const float*)d_in[10];
    const float* bl1 = (const float*)d_in[11];
    const float* Wl2 = (const float*)d_in[12];
    const float* bl2 = (const float*)d_in[13];

    int N = in_sizes[0] / 128;
    int E = in_sizes[1] / 2;
    const int* ei_src = ei;
    const int* ei_dst = ei + E;
    int NSB = (N + BNODES - 1) >> FSH;       // 782 buckets (<= NSBMAX)

    size_t Np = ((size_t)N + 3) & ~(size_t)3;
    // floats: 16 hdr + h1(Np*8) + s1 + d1 + h2(Np*8) + s2 + d2 = 16 + 20*Np
    // ints: bcur NSB*16; pairs NSB*CAPB  (~22.5 MB total)
    size_t need_bytes = (16 + Np * 20) * 4 + (size_t)NSB * 16 * 4 + (size_t)NSB * CAPB * 4;
    if (ws_size < need_bytes) return;  // degrade to wrong-answer, never fault

    float*    ws    = (float*)d_ws;
    unsigned* gmax1 = (unsigned*)d_ws;       // [0]
    unsigned* gmax2 = gmax1 + 1;             // [1]
    __half* h1 = (__half*)(ws + 16);         // Np*16 halves
    float* s1 = ws + 16 + Np * 8;            // Np
    float* d1 = s1 + Np;                     // Np
    __half* h2 = (__half*)(d1 + Np);         // Np*16 halves (cols 10..15 zero)
    float* s2 = (float*)(h2) + Np * 8;       // Np
    float* d2 = s2 + Np;                     // Np
    int* bcur = (int*)(d2 + Np);             // NSB*16 (1 cursor per 64B)
    unsigned* pairs = (unsigned*)(bcur + (size_t)NSB * 16);  // NSB*CAPB

    hipLaunchKernelGGL(k_init, dim3((NSB + 255) / 256), dim3(256), 0, stream, gmax1, bcur, NSB);
    hipLaunchKernelGGL(k_gemm1, dim3((N + 63) / 64), dim3(256), 0, stream,
                       x, W1, a1s, a1d, h1, s1, d1, gmax1, N);
    hipLaunchKernelGGL(k_csplit, dim3((E + TILE - 1) / TILE), dim3(512), 0, stream,
                       ei_src, ei_dst, bcur, pairs, E, NSB);
    hipLaunchKernelGGL(k_agg1, dim3(NSB), dim3(512), 0, stream,
                       bcur, pairs, ei_src, ei_dst, s1, d1, h1, b1, W2, a2s, a2d,
                       h2, s2, d2, gmax1, gmax2, N, E);
    hipLaunchKernelGGL(k_agg2, dim3(NSB), dim3(512), 0, stream,
                       bcur, pairs, ei_src, ei_dst, s2, d2, h2, b2, Wl1, bl1, Wl2, bl2,
                       gmax2, (float*)d_out, N, E);
}